// Round 5
// baseline (474.876 us; speedup 1.0000x reference)
//
#include <hip/hip_runtime.h>
#include <hip/hip_bf16.h>

// ---------------------------------------------------------------------------
// VisualContrastAttention on MI355X (gfx950)
// B=32, N=1024 (32x32), C=768, heads=12, hd=64, pool 8x8=64 tokens
// Pipeline:
//   K0  cast x/Wqkv/Wproj f32->bf16
//   K1  qkv GEMM: bf16 MFMA, 2-phase double-buffered global_load_lds (BK=64),
//       XCD-chunk swizzle; q,k stored [b,h,n,d]; V stored vt[b,h,d,n]
//   K2a gq reduction + Wpos/Wneg embeddings -> ep/en[384][64] f32
//   K2b depthwise conv3x3+GELU+avgpool -> t_pos/t_neg (bf16)
//   K3  stage-1: 8-wave flash attn, KV split in 2 halves + LDS merge,
//       contrast+rmsnorm -> vct[bh][d][m] f32
//   K4  stage-2 MFMA attention + rmsnorm -> out_patch bf16
//   K5  proj GEMM (2-phase dbuf, XCD swizzle) + bias -> f32 d_out
// ---------------------------------------------------------------------------

typedef __attribute__((ext_vector_type(8))) short short8;
typedef __attribute__((ext_vector_type(4))) short bf16x4;
typedef __attribute__((ext_vector_type(4))) float f32x4;

#define DEV static __device__ __forceinline__

DEV unsigned short f2bf(float f) {
  unsigned int b; __builtin_memcpy(&b, &f, 4);
  unsigned int r = (b + 0x7FFFu + ((b >> 16) & 1u)) >> 16;
  return (unsigned short)r;
}
DEV float bf2f(unsigned short u) {
  unsigned int b = ((unsigned int)u) << 16;
  float f; __builtin_memcpy(&f, &b, 4);
  return f;
}

// async global(16B per lane) -> LDS(wave-uniform base + lane*16)
DEV void gload16(const unsigned short* g, unsigned short* l) {
  __builtin_amdgcn_global_load_lds(
      (const __attribute__((address_space(1))) unsigned int*)g,
      (__attribute__((address_space(3))) unsigned int*)l, 16, 0, 0);
}

// ---- workspace layout (bytes) ---------------------------------------------
constexpr size_t SZ_QKV = (size_t)32 * 12 * 1024 * 64 * 2;   // 50331648 bf16
constexpr size_t OFF_Q   = 0;
constexpr size_t OFF_K   = OFF_Q + SZ_QKV;                    //  50331648
constexpr size_t OFF_VT  = OFF_K + SZ_QKV;                    // 100663296  vt[bh][d][n] bf16
constexpr size_t OFF_TPB = OFF_VT + SZ_QKV;                   // 150994944  bf16 384*64*64
constexpr size_t OFF_TNB = OFF_TPB + 3145728;                 // 154140672
constexpr size_t OFF_VCT = OFF_TNB + 3145728;                 // 157286400  f32 vct[bh][d][m]
constexpr size_t OFF_OP  = OFF_VCT + 6291456;                 // 163577856  bf16 32768*768
constexpr size_t OFF_XB  = OFF_OP + SZ_QKV;                   // 213909504
constexpr size_t OFF_WQ  = OFF_XB + SZ_QKV;                   // 264241152
constexpr size_t OFF_WP  = OFF_WQ + 3538944;                  // 267780096
constexpr size_t OFF_EP  = OFF_WP + 1179648;                  // 268959744  f32 384*64
constexpr size_t OFF_EN  = OFF_EP + 98304;                    // 269058048

// ---- K0: f32 -> bf16 cast --------------------------------------------------
__global__ __launch_bounds__(256) void cast_kernel(const float* __restrict__ src,
                                                   unsigned short* __restrict__ dst, int n4) {
  int i = blockIdx.x * 256 + threadIdx.x;
  if (i >= n4) return;
  float4 v = reinterpret_cast<const float4*>(src)[i];
  ushort4 o;
  o.x = f2bf(v.x); o.y = f2bf(v.y); o.z = f2bf(v.z); o.w = f2bf(v.w);
  reinterpret_cast<ushort4*>(dst)[i] = o;
}

// staging helper: one BK=64 tile of A and B (two [128][32] chunks each)
DEV void stage_tile(const unsigned short* __restrict__ A,
                    const unsigned short* __restrict__ Bm,
                    unsigned short* As, unsigned short* Bs,
                    int row0, int col0, int k0, int w, int srow, int scol) {
#pragma unroll
  for (int kc = 0; kc < 2; ++kc)
#pragma unroll
    for (int j = 0; j < 2; ++j) {
      const int qs = w * 2 + j;                 // wave slot 0..7
      const int r = qs * 16 + srow;             // per-lane global row
      const int cg = k0 + kc * 32 + scol;
      gload16(A + (size_t)(row0 + r) * 768 + cg, As + kc * 4096 + qs * 512);
      gload16(Bm + (size_t)(col0 + r) * 768 + cg, Bs + kc * 4096 + qs * 512);
    }
}

// ---- K1: qkv GEMM, M=32768 N=2304 K=768; q,k normal; v transposed ---------
// 128x128 tile, 4 waves, BK=64, 2-phase double-buffered, XCD swizzle.
__global__ __launch_bounds__(256) void gemm_qkv_kernel(const unsigned short* __restrict__ A,
    const unsigned short* __restrict__ Bm, unsigned short* __restrict__ q,
    unsigned short* __restrict__ k, unsigned short* __restrict__ vt) {
  __shared__ unsigned short As[2][8192];        // [buf][kc*4096 + slot*512]
  __shared__ unsigned short Bs[2][8192];
  const int t = threadIdx.x;
  const int lane = t & 63;
  const int w = t >> 6;
  const int wm = w >> 1, wn = w & 1;
  // XCD-chunk swizzle: nwg=4608 (8*576); consecutive logical ids per XCD
  const int id = blockIdx.x;
  const int swz = (id & 7) * 576 + (id >> 3);
  const int row0 = (swz / 18) * 128;
  const int col0 = (swz % 18) * 128;
  f32x4 acc[4][4];
#pragma unroll
  for (int i = 0; i < 4; ++i)
#pragma unroll
    for (int j = 0; j < 4; ++j) acc[i][j] = (f32x4){0.f, 0.f, 0.f, 0.f};
  const int l = lane & 15, g = lane >> 4;
  const int srow = lane >> 2, scol = (lane & 3) << 3;

  stage_tile(A, Bm, As[0], Bs[0], row0, col0, 0, w, srow, scol);
  __syncthreads();
  for (int kt = 0; kt < 12; ++kt) {
    const int cur = kt & 1;
    if (kt < 11)
      stage_tile(A, Bm, As[cur ^ 1], Bs[cur ^ 1], row0, col0, (kt + 1) * 64, w, srow, scol);
#pragma unroll
    for (int kc = 0; kc < 2; ++kc) {
      short8 af[4], bfv[4];
#pragma unroll
      for (int mt = 0; mt < 4; ++mt)
        af[mt] = *reinterpret_cast<const short8*>(As[cur] + kc * 4096 + (wm * 64 + mt * 16 + l) * 32 + g * 8);
#pragma unroll
      for (int nt = 0; nt < 4; ++nt)
        bfv[nt] = *reinterpret_cast<const short8*>(Bs[cur] + kc * 4096 + (wn * 64 + nt * 16 + l) * 32 + g * 8);
#pragma unroll
      for (int mt = 0; mt < 4; ++mt)
#pragma unroll
        for (int nt = 0; nt < 4; ++nt)
          acc[mt][nt] = __builtin_amdgcn_mfma_f32_16x16x32_bf16(af[mt], bfv[nt], acc[mt][nt], 0, 0, 0);
    }
    __syncthreads();
  }
  const int s_ = col0 / 768;
  if (s_ == 2) {
#pragma unroll
    for (int nt = 0; nt < 4; ++nt) {
      const int colin = wn * 64 + nt * 16 + l;
      const int head = ((col0 % 768) + colin) >> 6;
      const int d = colin & 63;
#pragma unroll
      for (int mt = 0; mt < 4; ++mt) {
        const int row = row0 + wm * 64 + mt * 16 + (g << 2);
        const int b = row >> 10, n = row & 1023;
        ushort4 pk;
        pk.x = f2bf(acc[mt][nt][0]); pk.y = f2bf(acc[mt][nt][1]);
        pk.z = f2bf(acc[mt][nt][2]); pk.w = f2bf(acc[mt][nt][3]);
        *reinterpret_cast<ushort4*>(vt + ((((size_t)b * 12 + head) * 64 + d) << 10) + n) = pk;
      }
    }
  } else {
    unsigned short* dst = (s_ == 0) ? q : k;
#pragma unroll
    for (int nt = 0; nt < 4; ++nt) {
      const int colin = wn * 64 + nt * 16 + l;
      const int head = ((col0 % 768) + colin) >> 6;
      const int d = colin & 63;
#pragma unroll
      for (int mt = 0; mt < 4; ++mt) {
#pragma unroll
        for (int r = 0; r < 4; ++r) {
          const int row = row0 + wm * 64 + mt * 16 + (g << 2) + r;
          const int b = row >> 10, n = row & 1023;
          dst[(((size_t)b * 12 + head) * 1024 + n) * 64 + d] = f2bf(acc[mt][nt][r]);
        }
      }
    }
  }
}

// ---- K2a: gq reduction + e+/e- embeddings ---------------------------------
__global__ __launch_bounds__(256) void gq_embed_kernel(const unsigned short* __restrict__ qg,
    const float* __restrict__ Wpos, const float* __restrict__ Wneg,
    float* __restrict__ ep, float* __restrict__ en) {
  const int bh = blockIdx.x;               // 0..383
  const unsigned short* qp = qg + (size_t)bh * 65536;
  __shared__ float red2[32][64];
  __shared__ float gq_s[64];
  const int t = threadIdx.x;
  const int c8 = (t & 7) << 3;
  const int part = t >> 3;                 // 0..31
  float s[8] = {0.f, 0.f, 0.f, 0.f, 0.f, 0.f, 0.f, 0.f};
  for (int i = 0; i < 32; ++i) {
    const short8 v = *reinterpret_cast<const short8*>(qp + (size_t)(part * 32 + i) * 64 + c8);
#pragma unroll
    for (int j = 0; j < 8; ++j) s[j] += bf2f((unsigned short)v[j]);
  }
#pragma unroll
  for (int j = 0; j < 8; ++j) red2[part][c8 + j] = s[j];
  __syncthreads();
  if (t < 64) {
    float s2 = 0.f;
    for (int p = 0; p < 32; ++p) s2 += red2[p][t];
    gq_s[t] = s2 * (1.0f / 1024.0f);
  }
  __syncthreads();
  if (t < 128) {
    const int d2 = t & 63;
    const float* Wm = (t < 64) ? Wpos : Wneg;
    float e = 0.f;
    for (int dd = 0; dd < 64; ++dd) e += gq_s[dd] * Wm[d2 * 64 + dd];
    (t < 64 ? ep : en)[bh * 64 + d2] = e;
  }
}

// ---- K2b: conv3x3 depthwise + GELU + 4x4 mean pool -> t_pos/t_neg ---------
__global__ __launch_bounds__(256) void conv_pool_kernel(const unsigned short* __restrict__ qg,
    const float* __restrict__ conv_w, const float* __restrict__ ep,
    const float* __restrict__ en, unsigned short* __restrict__ t_pos,
    unsigned short* __restrict__ t_neg) {
  const int bh = blockIdx.x;
  const int quad = blockIdx.y;             // y rows quad*8 .. quad*8+7
  const unsigned short* qp = qg + (size_t)bh * 65536;
  __shared__ float pool_s[16][64];
  const int t = threadIdx.x;
  const int dg = t & 7, sp = t >> 3;       // sp = x position 0..31
  const int d0 = dg << 3;
  float cw[3][3][8];
#pragma unroll
  for (int ky = 0; ky < 3; ++ky)
#pragma unroll
    for (int kx = 0; kx < 3; ++kx)
#pragma unroll
      for (int j = 0; j < 8; ++j)
        cw[ky][kx][j] = conv_w[(d0 + j) * 9 + ky * 3 + kx];
#pragma unroll
  for (int pyl = 0; pyl < 2; ++pyl) {
    float win[8] = {0.f, 0.f, 0.f, 0.f, 0.f, 0.f, 0.f, 0.f};
#pragma unroll
    for (int iy = 0; iy < 4; ++iy) {
      const int y = quad * 8 + pyl * 4 + iy;
      float a[8] = {0.f, 0.f, 0.f, 0.f, 0.f, 0.f, 0.f, 0.f};
#pragma unroll
      for (int ky = 0; ky < 3; ++ky) {
        const int yy = y + ky - 1;
        if (yy < 0 || yy > 31) continue;
#pragma unroll
        for (int kx = 0; kx < 3; ++kx) {
          const int xx = sp + kx - 1;
          if (xx < 0 || xx > 31) continue;
          const short8 v = *reinterpret_cast<const short8*>(qp + (size_t)(yy * 32 + xx) * 64 + d0);
#pragma unroll
          for (int j = 0; j < 8; ++j) a[j] += bf2f((unsigned short)v[j]) * cw[ky][kx][j];
        }
      }
#pragma unroll
      for (int j = 0; j < 8; ++j)
        win[j] += 0.5f * a[j] * (1.0f + erff(a[j] * 0.70710678118654752440f));
    }
#pragma unroll
    for (int j = 0; j < 8; ++j) {
      win[j] += __shfl_xor(win[j], 8);
      win[j] += __shfl_xor(win[j], 16);
    }
    if ((sp & 3) == 0) {
      const int px = sp >> 2;
#pragma unroll
      for (int j = 0; j < 8; ++j) pool_s[pyl * 8 + px][d0 + j] = win[j];
    }
  }
  __syncthreads();
#pragma unroll
  for (int i = 0; i < 4; ++i) {
    const int idx = i * 256 + t;           // 0..1023
    const int m = idx >> 6, dd = idx & 63;
    const int mg = quad * 16 + m;
    const float base = pool_s[m][dd] * (1.0f / 16.0f);
    t_pos[(size_t)bh * 4096 + mg * 64 + dd] = f2bf(base + ep[bh * 64 + dd]);
    t_neg[(size_t)bh * 4096 + mg * 64 + dd] = f2bf(base + en[bh * 64 + dd]);
  }
}

// ---- K3: stage-1 flash attention, 8 waves, KV split in 2 halves -----------
// wave w: strip = w&3 (t-tokens strip*16..+15), half = w>>2 (kv half*512..).
// Swapped QK^T: S^T[n][m]; lane m=l, n=tile*16+4g+r.  P feeds mfma16 A-frag.
// LDS (55296B): tp(9216) tn(9216) Ks0 Vts0 Ks1 Vts1 (9216 each);
// after loop Ks/Vts region is reused as merge scratch.
__global__ __launch_bounds__(512) void stage1_kernel(const unsigned short* __restrict__ kg,
    const unsigned short* __restrict__ vtg, const unsigned short* __restrict__ tpb,
    const unsigned short* __restrict__ tnb, const float* __restrict__ lam1p,
    const float* __restrict__ norm1_w, float* __restrict__ vct) {
  const int bh = blockIdx.x;
  __shared__ __align__(16) char smem[55296];
  unsigned short* tp = (unsigned short*)(smem);
  unsigned short* tn = (unsigned short*)(smem + 9216);
  const int t = threadIdx.x;
  const int lane = t & 63;
  const int w = t >> 6;
  const int half = w >> 2, strip = w & 3;
  const int th = t & 255;
  const int l = lane & 15, g = lane >> 4;
  unsigned short* Ks  = (unsigned short*)(smem + 18432 + half * 18432);
  unsigned short* Vts = (unsigned short*)(smem + 18432 + half * 18432 + 9216);
  { // load t_pos/t_neg: 512 threads, 512 rows-of-8
    const int r = t >> 3, c = (t & 7) << 3;
    *reinterpret_cast<short8*>(tp + r * 72 + c) =
        *reinterpret_cast<const short8*>(tpb + (size_t)bh * 4096 + r * 64 + c);
    *reinterpret_cast<short8*>(tn + r * 72 + c) =
        *reinterpret_cast<const short8*>(tnb + (size_t)bh * 4096 + r * 64 + c);
  }
  __syncthreads();
  short8 tf[2][2];
#pragma unroll
  for (int h = 0; h < 2; ++h) {
    tf[0][h] = *reinterpret_cast<const short8*>(tp + (strip * 16 + l) * 72 + h * 32 + g * 8);
    tf[1][h] = *reinterpret_cast<const short8*>(tn + (strip * 16 + l) * 72 + h * 32 + g * 8);
  }
  float Mo[2] = {-1e30f, -1e30f}, Lo[2] = {0.f, 0.f};
  f32x4 acc[2][4];
#pragma unroll
  for (int pp = 0; pp < 2; ++pp)
#pragma unroll
    for (int dt = 0; dt < 4; ++dt) acc[pp][dt] = (f32x4){0.f, 0.f, 0.f, 0.f};
  const size_t kbase = (size_t)bh * 65536;

  for (int it = 0; it < 8; ++it) {
    const int n0 = half * 512 + it * 64;
    __syncthreads();
    for (int L = th; L < 512; L += 256) {
      const int r = L >> 3, c = (L & 7) << 3;
      *reinterpret_cast<short8*>(Ks + r * 72 + c) =
          *reinterpret_cast<const short8*>(kg + kbase + (size_t)(n0 + r) * 64 + c);
      *reinterpret_cast<short8*>(Vts + r * 72 + c) =
          *reinterpret_cast<const short8*>(vtg + kbase + (size_t)r * 1024 + n0 + c);
    }
    __syncthreads();
    short8 kf[4][2];
#pragma unroll
    for (int tile = 0; tile < 4; ++tile)
#pragma unroll
      for (int h = 0; h < 2; ++h)
        kf[tile][h] = *reinterpret_cast<const short8*>(Ks + (tile * 16 + l) * 72 + h * 32 + g * 8);
    bf16x4 pf[2][4];
#pragma unroll
    for (int pp = 0; pp < 2; ++pp) {
      f32x4 s[4];
#pragma unroll
      for (int tile = 0; tile < 4; ++tile) {
        s[tile] = (f32x4){0.f, 0.f, 0.f, 0.f};
#pragma unroll
        for (int h = 0; h < 2; ++h)
          s[tile] = __builtin_amdgcn_mfma_f32_16x16x32_bf16(kf[tile][h], tf[pp][h], s[tile], 0, 0, 0);
      }
      float p[4][4];
      float tmax = -1e30f;
#pragma unroll
      for (int tile = 0; tile < 4; ++tile)
#pragma unroll
        for (int r = 0; r < 4; ++r) {
          const float v = s[tile][r] * 0.125f;
          p[tile][r] = v;
          tmax = fmaxf(tmax, v);
        }
      tmax = fmaxf(tmax, __shfl_xor(tmax, 16));
      tmax = fmaxf(tmax, __shfl_xor(tmax, 32));
      const float nm = fmaxf(Mo[pp], tmax);
      const float al = __expf(Mo[pp] - nm);
      Mo[pp] = nm;
      float ps = 0.f;
#pragma unroll
      for (int tile = 0; tile < 4; ++tile)
#pragma unroll
        for (int r = 0; r < 4; ++r) {
          const float e = __expf(p[tile][r] - nm);
          p[tile][r] = e;
          ps += e;
        }
      ps += __shfl_xor(ps, 16);
      ps += __shfl_xor(ps, 32);
      Lo[pp] = Lo[pp] * al + ps;
#pragma unroll
      for (int tile = 0; tile < 4; ++tile) {
        bf16x4 pk;
        pk[0] = (short)f2bf(p[tile][0]); pk[1] = (short)f2bf(p[tile][1]);
        pk[2] = (short)f2bf(p[tile][2]); pk[3] = (short)f2bf(p[tile][3]);
        pf[pp][tile] = pk;
      }
      float ar[4];
#pragma unroll
      for (int r = 0; r < 4; ++r) ar[r] = __shfl(al, 4 * g + r);
#pragma unroll
      for (int dt = 0; dt < 4; ++dt)
#pragma unroll
        for (int r = 0; r < 4; ++r) acc[pp][dt][r] *= ar[r];
    }
#pragma unroll
    for (int tile = 0; tile < 4; ++tile)
#pragma unroll
      for (int dt = 0; dt < 4; ++dt) {
        const bf16x4 vf = *reinterpret_cast<const bf16x4*>(Vts + (dt * 16 + l) * 72 + tile * 16 + g * 4);
        acc[0][dt] = __builtin_amdgcn_mfma_f32_16x16x16bf16_1k(pf[0][tile], vf, acc[0][dt], 0, 0, 0);
        acc[1][dt] = __builtin_amdgcn_mfma_f32_16x16x16bf16_1k(pf[1][tile], vf, acc[1][dt], 0, 0, 0);
      }
  }
  // ---- merge halves (scratch overlays Ks/Vts region) ----
  __syncthreads();
  float* accS = (float*)(smem + 18432);            // [strip][pp][dt][lane] f32x4
  float* moS  = (float*)(smem + 51200);            // [strip][pp][16]
  float* loS  = (float*)(smem + 51712);            // [strip][pp][16]
  if (half == 1) {
#pragma unroll
    for (int pp = 0; pp < 2; ++pp) {
#pragma unroll
      for (int dt = 0; dt < 4; ++dt)
        *reinterpret_cast<f32x4*>(accS + ((((strip * 2 + pp) * 4 + dt) * 64) + lane) * 4) = acc[pp][dt];
      if (g == 0) {
        moS[(strip * 2 + pp) * 16 + l] = Mo[pp];
        loS[(strip * 2 + pp) * 16 + l] = Lo[pp];
      }
    }
  }
  __syncthreads();
  if (half == 0) {
#pragma unroll
    for (int pp = 0; pp < 2; ++pp) {
      const float m1v = moS[(strip * 2 + pp) * 16 + l];
      const float l1v = loS[(strip * 2 + pp) * 16 + l];
      const float nm = fmaxf(Mo[pp], m1v);
      const float a0 = __expf(Mo[pp] - nm);
      const float a1 = __expf(m1v - nm);
      Lo[pp] = Lo[pp] * a0 + l1v * a1;
      float a0r[4], a1r[4];
#pragma unroll
      for (int r = 0; r < 4; ++r) {
        a0r[r] = __shfl(a0, 4 * g + r);
        a1r[r] = __shfl(a1, 4 * g + r);
      }
#pragma unroll
      for (int dt = 0; dt < 4; ++dt) {
        const f32x4 o = *reinterpret_cast<const f32x4*>(accS + ((((strip * 2 + pp) * 4 + dt) * 64) + lane) * 4);
#pragma unroll
        for (int r = 0; r < 4; ++r)
          acc[pp][dt][r] = acc[pp][dt][r] * a0r[r] + o[r] * a1r[r];
      }
    }
    const float inv0 = 1.f / Lo[0], inv1 = 1.f / Lo[1];
    float i1r[4], i2r[4];
#pragma unroll
    for (int r = 0; r < 4; ++r) {
      i1r[r] = __shfl(inv0, 4 * g + r);
      i2r[r] = __shfl(inv1, 4 * g + r);
    }
    const float lam1 = lam1p[0];
    float od[4][4], ss[4] = {0.f, 0.f, 0.f, 0.f};
#pragma unroll
    for (int dt = 0; dt < 4; ++dt)
#pragma unroll
      for (int r = 0; r < 4; ++r) {
        const float v = acc[0][dt][r] * i1r[r] - lam1 * (acc[1][dt][r] * i2r[r]);
        od[dt][r] = v;
        ss[r] += v * v;
      }
#pragma unroll
    for (int r = 0; r < 4; ++r) {
      ss[r] += __shfl_xor(ss[r], 1);
      ss[r] += __shfl_xor(ss[r], 2);
      ss[r] += __shfl_xor(ss[r], 4);
      ss[r] += __shfl_xor(ss[r], 8);
    }
    float sc[4];
#pragma unroll
    for (int r = 0; r < 4; ++r) sc[r] = 0.5f / (sqrtf(ss[r]) * 0.125f + 1e-6f);
    const int mb = strip * 16 + 4 * g;
#pragma unroll
    for (int dt = 0; dt < 4; ++dt) {
      const int dd = dt * 16 + l;
      const float nw = norm1_w[dd];
#pragma unroll
      for (int r = 0; r < 4; ++r)
        vct[(size_t)bh * 4096 + dd * 64 + mb + r] = od[dt][r] * sc[r] * nw;
    }
  }
}

// ---- K4: stage-2 MFMA attention + rmsnorm -> out_patch bf16 ---------------
__global__ __launch_bounds__(256) void stage2_kernel(const unsigned short* __restrict__ qg,
    const unsigned short* __restrict__ tpb, const unsigned short* __restrict__ tnb,
    const float* __restrict__ vct, const float* __restrict__ lam2p,
    const float* __restrict__ norm2_w, unsigned short* __restrict__ opb) {
  const int bh = blockIdx.x;
  const int q0 = blockIdx.y * 64;
  __shared__ unsigned short tp[64 * 72], tn[64 * 72], Qs[64 * 72], Vc[64 * 72];
  const int t = threadIdx.x;
  const int lane = t & 63;
  const int w = t >> 6;
  const int l = lane & 15, g = lane >> 4;
  for (int L = t; L < 512; L += 256) {
    const int r = L >> 3, c = (L & 7) << 3;
    *reinterpret_cast<short8*>(tp + r * 72 + c) =
        *reinterpret_cast<const short8*>(tpb + (size_t)bh * 4096 + r * 64 + c);
    *reinterpret_cast<short8*>(tn + r * 72 + c) =
        *reinterpret_cast<const short8*>(tnb + (size_t)bh * 4096 + r * 64 + c);
    *reinterpret_cast<short8*>(Qs + r * 72 + c) =
        *reinterpret_cast<const short8*>(qg + (size_t)bh * 65536 + (size_t)(q0 + r) * 64 + c);
  }
  for (int L = t; L < 4096; L += 256) {
    const int dd = L >> 6, m = L & 63;
    Vc[dd * 72 + m] = f2bf(vct[(size_t)bh * 4096 + L]);
  }
  __syncthreads();
  short8 qf[2];
#pragma unroll
  for (int h = 0; h < 2; ++h)
    qf[h] = *reinterpret_cast<const short8*>(Qs + (w * 16 + l) * 72 + h * 32 + g * 8);
  bf16x4 vcf[4][4];
#pragma unroll
  for (int tile = 0; tile < 4; ++tile)
#pragma unroll
    for (int dt = 0; dt < 4; ++dt)
      vcf[tile][dt] = *reinterpret_cast<const bf16x4*>(Vc + (dt * 16 + l) * 72 + tile * 16 + g * 4);
  bf16x4 pf[2][4];
#pragma unroll
  for (int pp = 0; pp < 2; ++pp) {
    const unsigned short* tm = pp ? tn : tp;
    f32x4 s[4];
#pragma unroll
    for (int tile = 0; tile < 4; ++tile) {
      s[tile] = (f32x4){0.f, 0.f, 0.f, 0.f};
#pragma unroll
      for (int h = 0; h < 2; ++h) {
        const short8 tfb = *reinterpret_cast<const short8*>(tm + (tile * 16 + l) * 72 + h * 32 + g * 8);
        s[tile] = __builtin_amdgcn_mfma_f32_16x16x32_bf16(tfb, qf[h], s[tile], 0, 0, 0);
      }
    }
    float p[4][4];
    float lmax = -1e30f;
#pragma unroll
    for (int tile = 0; tile < 4; ++tile)
#pragma unroll
      for (int r = 0; r < 4; ++r) {
        const float v = s[tile][r] * 0.125f;
        p[tile][r] = v;
        lmax = fmaxf(lmax, v);
      }
    lmax = fmaxf(lmax, __shfl_xor(lmax, 16));
    lmax = fmaxf(lmax, __shfl_xor(lmax, 32));
    float ps = 0.f;
#pragma unroll
    for (int tile = 0; tile < 4; ++tile)
#pragma unroll
      for (int r = 0; r < 4; ++r) {
        const float e = __expf(p[tile][r] - lmax);
        p[tile][r] = e;
        ps += e;
      }
    ps += __shfl_xor(ps, 16);
    ps += __shfl_xor(ps, 32);
    const float inv = 1.f / ps;
#pragma unroll
    for (int tile = 0; tile < 4; ++tile) {
      bf16x4 pk;
      pk[0] = (short)f2bf(p[tile][0] * inv); pk[1] = (short)f2bf(p[tile][1] * inv);
      pk[2] = (short)f2bf(p[tile][2] * inv); pk[3] = (short)f2bf(p[tile][3] * inv);
      pf[pp][tile] = pk;
    }
  }
  f32x4 a1[4], a2[4];
#pragma unroll
  for (int dt = 0; dt < 4; ++dt) {
    a1[dt] = (f32x4){0.f, 0.f, 0.f, 0.f};
    a2[dt] = (f32x4){0.f, 0.f, 0.f, 0.f};
  }
#pragma unroll
  for (int tile = 0; tile < 4; ++tile)
#pragma unroll
    for (int dt = 0; dt < 4; ++dt) {
      a1[dt] = __builtin_amdgcn_mfma_f32_16x16x16bf16_1k(pf[0][tile], vcf[tile][dt], a1[dt], 0, 0, 0);
      a2[dt] = __builtin_amdgcn_mfma_f32_16x16x16bf16_1k(pf[1][tile], vcf[tile][dt], a2[dt], 0, 0, 0);
    }
  const float lam2 = lam2p[0];
  float od[4][4], ss[4] = {0.f, 0.f, 0.f, 0.f};
#pragma unroll
  for (int dt = 0; dt < 4; ++dt)
#pragma unroll
    for (int r = 0; r < 4; ++r) {
      const float v = a1[dt][r] - lam2 * a2[dt][r];
      od[dt][r] = v;
      ss[r] += v * v;
    }
#pragma unroll
  for (int r = 0; r < 4; ++r) {
    ss[r] += __shfl_xor(ss[r], 1);
    ss[r] += __shfl_xor(ss[r], 2);
    ss[r] += __shfl_xor(ss[r], 4);
    ss[r] += __shfl_xor(ss[r], 8);
  }
  float sc[4];
#pragma unroll
  for (int r = 0; r < 4; ++r) sc[r] = 0.5f / (sqrtf(ss[r]) * 0.125f + 1e-6f);
  const int b = bh / 12, head = bh % 12;
  const size_t ob = ((size_t)b * 1024 + q0 + w * 16 + 4 * g) * 768 + head * 64;
#pragma unroll
  for (int dt = 0; dt < 4; ++dt) {
    const float nw = norm2_w[dt * 16 + l];
#pragma unroll
    for (int r = 0; r < 4; ++r)
      opb[ob + (size_t)r * 768 + dt * 16 + l] = f2bf(od[dt][r] * sc[r] * nw);
  }
}

// ---- K5: projection GEMM, M=32768 N=768 K=768, +bias, f32 out -------------
__global__ __launch_bounds__(256) void gemm_proj_kernel(const unsigned short* __restrict__ A,
    const unsigned short* __restrict__ Bm, const float* __restrict__ bias,
    float* __restrict__ out) {
  __shared__ unsigned short As[2][8192];
  __shared__ unsigned short Bs[2][8192];
  const int t = threadIdx.x;
  const int lane = t & 63;
  const int w = t >> 6;
  const int wm = w >> 1, wn = w & 1;
  // XCD-chunk swizzle: nwg=1536 (8*192)
  const int id = blockIdx.x;
  const int swz = (id & 7) * 192 + (id >> 3);
  const int row0 = (swz / 6) * 128;
  const int col0 = (swz % 6) * 128;
  f32x4 acc[4][4];
#pragma unroll
  for (int i = 0; i < 4; ++i)
#pragma unroll
    for (int j = 0; j < 4; ++j) acc[i][j] = (f32x4){0.f, 0.f, 0.f, 0.f};
  const int l = lane & 15, g = lane >> 4;
  const int srow = lane >> 2, scol = (lane & 3) << 3;

  stage_tile(A, Bm, As[0], Bs[0], row0, col0, 0, w, srow, scol);
  __syncthreads();
  for (int kt = 0; kt < 12; ++kt) {
    const int cur = kt & 1;
    if (kt < 11)
      stage_tile(A, Bm, As[cur ^ 1], Bs[cur ^ 1], row0, col0, (kt + 1) * 64, w, srow, scol);
#pragma unroll
    for (int kc = 0; kc < 2; ++kc) {
      short8 af[4], bfv[4];
#pragma unroll
      for (int mt = 0; mt < 4; ++mt)
        af[mt] = *reinterpret_cast<const short8*>(As[cur] + kc * 4096 + (wm * 64 + mt * 16 + l) * 32 + g * 8);
#pragma unroll
      for (int nt = 0; nt < 4; ++nt)
        bfv[nt] = *reinterpret_cast<const short8*>(Bs[cur] + kc * 4096 + (wn * 64 + nt * 16 + l) * 32 + g * 8);
#pragma unroll
      for (int mt = 0; mt < 4; ++mt)
#pragma unroll
        for (int nt = 0; nt < 4; ++nt)
          acc[mt][nt] = __builtin_amdgcn_mfma_f32_16x16x32_bf16(af[mt], bfv[nt], acc[mt][nt], 0, 0, 0);
    }
    __syncthreads();
  }
#pragma unroll
  for (int nt = 0; nt < 4; ++nt) {
    const int col = col0 + wn * 64 + nt * 16 + l;
    const float bv = bias[col];
#pragma unroll
    for (int mt = 0; mt < 4; ++mt)
#pragma unroll
      for (int r = 0; r < 4; ++r) {
        const int row = row0 + wm * 64 + mt * 16 + (g << 2) + r;
        out[(size_t)row * 768 + col] = acc[mt][nt][r] + bv;
      }
  }
}

// ---------------------------------------------------------------------------
extern "C" void kernel_launch(void* const* d_in, const int* in_sizes, int n_in,
                              void* d_out, int out_size, void* d_ws, size_t ws_size,
                              hipStream_t stream) {
  (void)in_sizes; (void)n_in; (void)out_size; (void)ws_size;
  const float* x       = (const float*)d_in[0];
  const float* Wqkv    = (const float*)d_in[1];
  const float* Wproj   = (const float*)d_in[2];
  const float* bproj   = (const float*)d_in[3];
  const float* Wpos    = (const float*)d_in[4];
  const float* Wneg    = (const float*)d_in[5];
  const float* conv_w  = (const float*)d_in[6];
  const float* lam1    = (const float*)d_in[7];
  const float* lam2    = (const float*)d_in[8];
  const float* norm1_w = (const float*)d_in[9];
  const float* norm2_w = (const float*)d_in[10];
  float* out = (float*)d_out;
  char* ws = (char*)d_ws;
  unsigned short* qb   = (unsigned short*)(ws + OFF_Q);
  unsigned short* kb   = (unsigned short*)(ws + OFF_K);
  unsigned short* vtb  = (unsigned short*)(ws + OFF_VT);
  unsigned short* tpbb = (unsigned short*)(ws + OFF_TPB);
  unsigned short* tnbb = (unsigned short*)(ws + OFF_TNB);
  float* vctb          = (float*)(ws + OFF_VCT);
  unsigned short* opb  = (unsigned short*)(ws + OFF_OP);
  unsigned short* xb   = (unsigned short*)(ws + OFF_XB);
  unsigned short* wqb  = (unsigned short*)(ws + OFF_WQ);
  unsigned short* wpb  = (unsigned short*)(ws + OFF_WP);
  float* epb           = (float*)(ws + OFF_EP);
  float* enb           = (float*)(ws + OFF_EN);

  cast_kernel<<<dim3(6291456 / 256), dim3(256), 0, stream>>>(x, xb, 6291456);
  cast_kernel<<<dim3(442368 / 256), dim3(256), 0, stream>>>(Wqkv, wqb, 442368);
  cast_kernel<<<dim3(147456 / 256), dim3(256), 0, stream>>>(Wproj, wpb, 147456);
  gemm_qkv_kernel<<<dim3(4608), dim3(256), 0, stream>>>(xb, wqb, qb, kb, vtb);
  gq_embed_kernel<<<dim3(384), dim3(256), 0, stream>>>(qb, Wpos, Wneg, epb, enb);
  conv_pool_kernel<<<dim3(384, 4), dim3(256), 0, stream>>>(qb, conv_w, epb, enb, tpbb, tnbb);
  stage1_kernel<<<dim3(384), dim3(512), 0, stream>>>(kb, vtb, tpbb, tnbb, lam1, norm1_w, vctb);
  stage2_kernel<<<dim3(384, 16), dim3(256), 0, stream>>>(qb, tpbb, tnbb, vctb, lam2, norm2_w, opb);
  gemm_proj_kernel<<<dim3(1536), dim3(256), 0, stream>>>(opb, wpb, bproj, out);
}

// Round 6
// 435.159 us; speedup vs baseline: 1.0913x; 1.0913x over previous
//
#include <hip/hip_runtime.h>
#include <hip/hip_bf16.h>

// ---------------------------------------------------------------------------
// VisualContrastAttention on MI355X (gfx950)
// B=32, N=1024 (32x32), C=768, heads=12, hd=64, pool 8x8=64 tokens
// Pipeline:
//   K0  cast x/Wqkv/Wproj f32->bf16
//   K1  qkv GEMM: 256x256 tile, 8-wave, BK=64, 8-phase counted-vmcnt schedule
//       (T1 XCD swizzle + T2 LDS XOR swizzle + T3/T4 + T5 setprio);
//       q,k stored [b,h,n,d]; V stored TRANSPOSED vt[b,h,d,n]
//   K2a gq reduction + Wpos/Wneg embeddings -> ep/en[384][64] f32
//   K2b depthwise conv3x3+GELU+avgpool -> t_pos/t_neg (bf16)
//   K3  stage-1: 4-wave swapped-QK^T MFMA flash (64 tok x 1024 kv),
//       contrast+rmsnorm -> vct[bh][d][m] f32
//   K4  stage-2 MFMA attention + rmsnorm -> out_patch bf16
//   K5  proj GEMM (128^2 2-phase dbuf, XCD swizzle) + bias -> f32 d_out
// ---------------------------------------------------------------------------

typedef __attribute__((ext_vector_type(8))) short short8;
typedef __attribute__((ext_vector_type(4))) short bf16x4;
typedef __attribute__((ext_vector_type(4))) float f32x4;

#define DEV static __device__ __forceinline__

DEV unsigned short f2bf(float f) {
  unsigned int b; __builtin_memcpy(&b, &f, 4);
  unsigned int r = (b + 0x7FFFu + ((b >> 16) & 1u)) >> 16;
  return (unsigned short)r;
}
DEV float bf2f(unsigned short u) {
  unsigned int b = ((unsigned int)u) << 16;
  float f; __builtin_memcpy(&f, &b, 4);
  return f;
}

// async global(16B per lane) -> LDS(wave-uniform base + lane*16)
DEV void gload16(const unsigned short* g, unsigned short* l) {
  __builtin_amdgcn_global_load_lds(
      (const __attribute__((address_space(1))) unsigned int*)g,
      (__attribute__((address_space(3))) unsigned int*)l, 16, 0, 0);
}

DEV void bar() {
  asm volatile("" ::: "memory");
  __builtin_amdgcn_s_barrier();
  asm volatile("" ::: "memory");
}
DEV void wait_vm4() { asm volatile("s_waitcnt vmcnt(4)" ::: "memory"); __builtin_amdgcn_sched_barrier(0); }
DEV void wait_vm0() { asm volatile("s_waitcnt vmcnt(0)" ::: "memory"); __builtin_amdgcn_sched_barrier(0); }

// ---- workspace layout (bytes) ---------------------------------------------
constexpr size_t SZ_QKV = (size_t)32 * 12 * 1024 * 64 * 2;   // 50331648 bf16
constexpr size_t OFF_Q   = 0;
constexpr size_t OFF_K   = OFF_Q + SZ_QKV;
constexpr size_t OFF_VT  = OFF_K + SZ_QKV;                    // vt[bh][d][n] bf16
constexpr size_t OFF_TPB = OFF_VT + SZ_QKV;                   // bf16 384*64*64
constexpr size_t OFF_TNB = OFF_TPB + 3145728;
constexpr size_t OFF_VCT = OFF_TNB + 3145728;                 // f32 vct[bh][d][m]
constexpr size_t OFF_OP  = OFF_VCT + 6291456;                 // bf16 32768*768
constexpr size_t OFF_XB  = OFF_OP + SZ_QKV;
constexpr size_t OFF_WQ  = OFF_XB + SZ_QKV;
constexpr size_t OFF_WP  = OFF_WQ + 3538944;
constexpr size_t OFF_EP  = OFF_WP + 1179648;                  // f32 384*64
constexpr size_t OFF_EN  = OFF_EP + 98304;

// ---- K0: f32 -> bf16 cast --------------------------------------------------
__global__ __launch_bounds__(256) void cast_kernel(const float* __restrict__ src,
                                                   unsigned short* __restrict__ dst, int n4) {
  int i = blockIdx.x * 256 + threadIdx.x;
  if (i >= n4) return;
  float4 v = reinterpret_cast<const float4*>(src)[i];
  ushort4 o;
  o.x = f2bf(v.x); o.y = f2bf(v.y); o.z = f2bf(v.z); o.w = f2bf(v.w);
  reinterpret_cast<ushort4*>(dst)[i] = o;
}

// ---- K1: qkv GEMM, 256^2 8-phase -------------------------------------------
// Grid 1152 (128 rowtiles x 9 coltiles), 512 thr (8 waves: wm=w>>2, wn=w&3).
// LDS 128KB: A[2][256][64] @0, B[2][256][64] @32768 (ushort units).
// Swizzle: LDS(row, physchunk p) = G(row, p ^ (row&7)); read chunk c -> phys c^(row&7).
// Per-ktile phases p1..p4: quadrants (mh,nh) = (0,0),(0,1),(1,1),(1,0);
// stages: p1:A-top(k+1->dbuf^1) p2:A-bot(k+1) p3:B-top(k+2->dbuf) p4:B-bot(k+2);
// boundary wait vmcnt(4) (vmcnt(0) before last ktile).
DEV void stage_ht(const unsigned short* __restrict__ G, unsigned short* shbase,
                  int grow0, int k0, int htrow0, int w, int lane) {
  const int rl = lane >> 3;
  const int ck = (lane & 7) ^ rl;
  const unsigned short* s0 = G + (size_t)(grow0 + htrow0 + w * 16 + rl) * 768 + k0 + ck * 8;
  gload16(s0, shbase + (htrow0 + w * 16) * 64);
  gload16(s0 + (size_t)8 * 768, shbase + (htrow0 + w * 16 + 8) * 64);
}

__global__ __launch_bounds__(512, 2) void gemm_qkv_kernel(const unsigned short* __restrict__ A,
    const unsigned short* __restrict__ Bm, unsigned short* __restrict__ q,
    unsigned short* __restrict__ k, unsigned short* __restrict__ vt) {
  __shared__ __align__(16) unsigned short sh[65536];   // 128 KiB
  const int t = threadIdx.x;
  const int lane = t & 63;
  const int w = t >> 6;                 // 0..7
  const int wm = w >> 2, wn = w & 3;    // 2 x 4 wave grid
  const int l = lane & 15, g = lane >> 4;
  // XCD swizzle (nwg = 1152 = 8*144)
  const int id = blockIdx.x;
  const int swz = (id & 7) * 144 + (id >> 3);
  const int rt = swz / 9, ct = swz % 9;
  const int row0 = rt * 256, col0 = ct * 256;

  f32x4 acc[8][4];
#pragma unroll
  for (int i = 0; i < 8; ++i)
#pragma unroll
    for (int j = 0; j < 4; ++j) acc[i][j] = (f32x4){0.f, 0.f, 0.f, 0.f};

  // prologue: k0 all 4 half-tiles + k1 B halves; wait oldest 8; barrier
  stage_ht(A, sh, row0, 0, 0, w, lane);
  stage_ht(A, sh, row0, 0, 128, w, lane);
  stage_ht(Bm, sh + 32768, col0, 0, 0, w, lane);
  stage_ht(Bm, sh + 32768, col0, 0, 128, w, lane);
  stage_ht(Bm, sh + 32768 + 16384, col0, 64, 0, w, lane);
  stage_ht(Bm, sh + 32768 + 16384, col0, 64, 128, w, lane);
  wait_vm4();
  bar();

  for (int m = 0; m < 12; ++m) {
    const int d = m & 1;
    const unsigned short* Ab = sh + d * 16384;
    const unsigned short* Bb = sh + 32768 + d * 16384;
    short8 af[4][2], bf0[2][2], bf1[2][2];
    // ---- p1: (mh0, nh0); stage A-top(k m+1) ----
#pragma unroll
    for (int mt = 0; mt < 4; ++mt)
#pragma unroll
      for (int kc = 0; kc < 2; ++kc) {
        const int r = wm * 128 + 0 * 64 + mt * 16 + l;
        af[mt][kc] = *reinterpret_cast<const short8*>(Ab + r * 64 + (((kc << 2) | g) ^ (r & 7)) * 8);
      }
#pragma unroll
    for (int nt = 0; nt < 2; ++nt)
#pragma unroll
      for (int kc = 0; kc < 2; ++kc) {
        const int r = wn * 64 + 0 * 32 + nt * 16 + l;
        bf0[nt][kc] = *reinterpret_cast<const short8*>(Bb + r * 64 + (((kc << 2) | g) ^ (r & 7)) * 8);
      }
    if (m + 1 < 12) stage_ht(A, sh + (d ^ 1) * 16384, row0, (m + 1) * 64, 0, w, lane);
    bar();
    __builtin_amdgcn_s_setprio(1);
#pragma unroll
    for (int kc = 0; kc < 2; ++kc)
#pragma unroll
      for (int mt = 0; mt < 4; ++mt)
#pragma unroll
        for (int nt = 0; nt < 2; ++nt)
          acc[mt][nt] = __builtin_amdgcn_mfma_f32_16x16x32_bf16(af[mt][kc], bf0[nt][kc], acc[mt][nt], 0, 0, 0);
    __builtin_amdgcn_s_setprio(0);
    bar();
    // ---- p2: (mh0, nh1); stage A-bot(k m+1) ----
#pragma unroll
    for (int nt = 0; nt < 2; ++nt)
#pragma unroll
      for (int kc = 0; kc < 2; ++kc) {
        const int r = wn * 64 + 32 + nt * 16 + l;
        bf1[nt][kc] = *reinterpret_cast<const short8*>(Bb + r * 64 + (((kc << 2) | g) ^ (r & 7)) * 8);
      }
    if (m + 1 < 12) stage_ht(A, sh + (d ^ 1) * 16384, row0, (m + 1) * 64, 128, w, lane);
    bar();
    __builtin_amdgcn_s_setprio(1);
#pragma unroll
    for (int kc = 0; kc < 2; ++kc)
#pragma unroll
      for (int mt = 0; mt < 4; ++mt)
#pragma unroll
        for (int nt = 0; nt < 2; ++nt)
          acc[mt][2 + nt] = __builtin_amdgcn_mfma_f32_16x16x32_bf16(af[mt][kc], bf1[nt][kc], acc[mt][2 + nt], 0, 0, 0);
    __builtin_amdgcn_s_setprio(0);
    bar();
    // ---- p3: (mh1, nh1); stage B-top(k m+2) ----
#pragma unroll
    for (int mt = 0; mt < 4; ++mt)
#pragma unroll
      for (int kc = 0; kc < 2; ++kc) {
        const int r = wm * 128 + 64 + mt * 16 + l;
        af[mt][kc] = *reinterpret_cast<const short8*>(Ab + r * 64 + (((kc << 2) | g) ^ (r & 7)) * 8);
      }
    if (m + 2 < 12) stage_ht(Bm, sh + 32768 + d * 16384, col0, (m + 2) * 64, 0, w, lane);
    bar();
    __builtin_amdgcn_s_setprio(1);
#pragma unroll
    for (int kc = 0; kc < 2; ++kc)
#pragma unroll
      for (int mt = 0; mt < 4; ++mt)
#pragma unroll
        for (int nt = 0; nt < 2; ++nt)
          acc[4 + mt][2 + nt] = __builtin_amdgcn_mfma_f32_16x16x32_bf16(af[mt][kc], bf1[nt][kc], acc[4 + mt][2 + nt], 0, 0, 0);
    __builtin_amdgcn_s_setprio(0);
    bar();
    // ---- p4: (mh1, nh0); stage B-bot(k m+2); boundary wait ----
    if (m + 2 < 12) stage_ht(Bm, sh + 32768 + d * 16384, col0, (m + 2) * 64, 128, w, lane);
    bar();
    __builtin_amdgcn_s_setprio(1);
#pragma unroll
    for (int kc = 0; kc < 2; ++kc)
#pragma unroll
      for (int mt = 0; mt < 4; ++mt)
#pragma unroll
        for (int nt = 0; nt < 2; ++nt)
          acc[4 + mt][nt] = __builtin_amdgcn_mfma_f32_16x16x32_bf16(af[mt][kc], bf0[nt][kc], acc[4 + mt][nt], 0, 0, 0);
    __builtin_amdgcn_s_setprio(0);
    if (m < 11) {
      if (m == 10) wait_vm0(); else wait_vm4();
    }
    bar();
  }

  // ---- epilogue ----
  const int s_ = ct / 3;                // 0 q, 1 k, 2 v
  if (s_ == 2) {
#pragma unroll
    for (int ni = 0; ni < 4; ++ni) {
      const int colg = (ct % 3) * 256 + wn * 64 + ni * 16 + l;
      const int head = colg >> 6, dd = colg & 63;
#pragma unroll
      for (int mi = 0; mi < 8; ++mi) {
        const int row = row0 + wm * 128 + mi * 16 + (g << 2);
        const int b = row >> 10, n = row & 1023;
        ushort4 pk;
        pk.x = f2bf(acc[mi][ni][0]); pk.y = f2bf(acc[mi][ni][1]);
        pk.z = f2bf(acc[mi][ni][2]); pk.w = f2bf(acc[mi][ni][3]);
        *reinterpret_cast<ushort4*>(vt + ((((size_t)b * 12 + head) * 64 + dd) << 10) + n) = pk;
      }
    }
  } else {
    unsigned short* dst = (s_ == 0) ? q : k;
#pragma unroll
    for (int ni = 0; ni < 4; ++ni) {
      const int colg = (ct % 3) * 256 + wn * 64 + ni * 16 + l;
      const int head = colg >> 6, dd = colg & 63;
#pragma unroll
      for (int mi = 0; mi < 8; ++mi) {
#pragma unroll
        for (int r = 0; r < 4; ++r) {
          const int row = row0 + wm * 128 + mi * 16 + (g << 2) + r;
          const int b = row >> 10, n = row & 1023;
          dst[(((size_t)b * 12 + head) * 1024 + n) * 64 + dd] = f2bf(acc[mi][ni][r]);
        }
      }
    }
  }
}

// ---- K2a: gq reduction + e+/e- embeddings ---------------------------------
__global__ __launch_bounds__(256) void gq_embed_kernel(const unsigned short* __restrict__ qg,
    const float* __restrict__ Wpos, const float* __restrict__ Wneg,
    float* __restrict__ ep, float* __restrict__ en) {
  const int bh = blockIdx.x;
  const unsigned short* qp = qg + (size_t)bh * 65536;
  __shared__ float red2[32][64];
  __shared__ float gq_s[64];
  const int t = threadIdx.x;
  const int c8 = (t & 7) << 3;
  const int part = t >> 3;
  float s[8] = {0.f, 0.f, 0.f, 0.f, 0.f, 0.f, 0.f, 0.f};
  for (int i = 0; i < 32; ++i) {
    const short8 v = *reinterpret_cast<const short8*>(qp + (size_t)(part * 32 + i) * 64 + c8);
#pragma unroll
    for (int j = 0; j < 8; ++j) s[j] += bf2f((unsigned short)v[j]);
  }
#pragma unroll
  for (int j = 0; j < 8; ++j) red2[part][c8 + j] = s[j];
  __syncthreads();
  if (t < 64) {
    float s2 = 0.f;
    for (int p = 0; p < 32; ++p) s2 += red2[p][t];
    gq_s[t] = s2 * (1.0f / 1024.0f);
  }
  __syncthreads();
  if (t < 128) {
    const int d2 = t & 63;
    const float* Wm = (t < 64) ? Wpos : Wneg;
    float e = 0.f;
    for (int dd = 0; dd < 64; ++dd) e += gq_s[dd] * Wm[d2 * 64 + dd];
    (t < 64 ? ep : en)[bh * 64 + d2] = e;
  }
}

// ---- K2b: conv3x3 depthwise + GELU + 4x4 mean pool -> t_pos/t_neg ---------
__global__ __launch_bounds__(256) void conv_pool_kernel(const unsigned short* __restrict__ qg,
    const float* __restrict__ conv_w, const float* __restrict__ ep,
    const float* __restrict__ en, unsigned short* __restrict__ t_pos,
    unsigned short* __restrict__ t_neg) {
  const int bh = blockIdx.x;
  const int quad = blockIdx.y;
  const unsigned short* qp = qg + (size_t)bh * 65536;
  __shared__ float pool_s[16][64];
  const int t = threadIdx.x;
  const int dg = t & 7, sp = t >> 3;
  const int d0 = dg << 3;
  float cw[3][3][8];
#pragma unroll
  for (int ky = 0; ky < 3; ++ky)
#pragma unroll
    for (int kx = 0; kx < 3; ++kx)
#pragma unroll
      for (int j = 0; j < 8; ++j)
        cw[ky][kx][j] = conv_w[(d0 + j) * 9 + ky * 3 + kx];
#pragma unroll
  for (int pyl = 0; pyl < 2; ++pyl) {
    float win[8] = {0.f, 0.f, 0.f, 0.f, 0.f, 0.f, 0.f, 0.f};
#pragma unroll
    for (int iy = 0; iy < 4; ++iy) {
      const int y = quad * 8 + pyl * 4 + iy;
      float a[8] = {0.f, 0.f, 0.f, 0.f, 0.f, 0.f, 0.f, 0.f};
#pragma unroll
      for (int ky = 0; ky < 3; ++ky) {
        const int yy = y + ky - 1;
        if (yy < 0 || yy > 31) continue;
#pragma unroll
        for (int kx = 0; kx < 3; ++kx) {
          const int xx = sp + kx - 1;
          if (xx < 0 || xx > 31) continue;
          const short8 v = *reinterpret_cast<const short8*>(qp + (size_t)(yy * 32 + xx) * 64 + d0);
#pragma unroll
          for (int j = 0; j < 8; ++j) a[j] += bf2f((unsigned short)v[j]) * cw[ky][kx][j];
        }
      }
#pragma unroll
      for (int j = 0; j < 8; ++j)
        win[j] += 0.5f * a[j] * (1.0f + erff(a[j] * 0.70710678118654752440f));
    }
#pragma unroll
    for (int j = 0; j < 8; ++j) {
      win[j] += __shfl_xor(win[j], 8);
      win[j] += __shfl_xor(win[j], 16);
    }
    if ((sp & 3) == 0) {
      const int px = sp >> 2;
#pragma unroll
      for (int j = 0; j < 8; ++j) pool_s[pyl * 8 + px][d0 + j] = win[j];
    }
  }
  __syncthreads();
#pragma unroll
  for (int i = 0; i < 4; ++i) {
    const int idx = i * 256 + t;
    const int m = idx >> 6, dd = idx & 63;
    const int mg = quad * 16 + m;
    const float base = pool_s[m][dd] * (1.0f / 16.0f);
    t_pos[(size_t)bh * 4096 + mg * 64 + dd] = f2bf(base + ep[bh * 64 + dd]);
    t_neg[(size_t)bh * 4096 + mg * 64 + dd] = f2bf(base + en[bh * 64 + dd]);
  }
}

// ---- K3: stage-1 MFMA flash attention + contrast + rmsnorm (4-wave) -------
__global__ __launch_bounds__(256) void stage1_kernel(const unsigned short* __restrict__ kg,
    const unsigned short* __restrict__ vtg, const unsigned short* __restrict__ tpb,
    const unsigned short* __restrict__ tnb, const float* __restrict__ lam1p,
    const float* __restrict__ norm1_w, float* __restrict__ vct) {
  const int bh = blockIdx.x;
  __shared__ unsigned short tp[64 * 72], tn[64 * 72];
  __shared__ unsigned short Ks[64 * 72], Vts[64 * 72];
  const int t = threadIdx.x;
  const int lane = t & 63;
  const int w = t >> 6;
  const int l = lane & 15, g = lane >> 4;
  for (int L = t; L < 512; L += 256) {
    const int r = L >> 3, c = (L & 7) << 3;
    *reinterpret_cast<short8*>(tp + r * 72 + c) =
        *reinterpret_cast<const short8*>(tpb + (size_t)bh * 4096 + r * 64 + c);
    *reinterpret_cast<short8*>(tn + r * 72 + c) =
        *reinterpret_cast<const short8*>(tnb + (size_t)bh * 4096 + r * 64 + c);
  }
  __syncthreads();
  short8 tf[2][2];
#pragma unroll
  for (int h = 0; h < 2; ++h) {
    tf[0][h] = *reinterpret_cast<const short8*>(tp + (w * 16 + l) * 72 + h * 32 + g * 8);
    tf[1][h] = *reinterpret_cast<const short8*>(tn + (w * 16 + l) * 72 + h * 32 + g * 8);
  }
  float Mo[2] = {-1e30f, -1e30f}, Lo[2] = {0.f, 0.f};
  f32x4 acc[2][4];
#pragma unroll
  for (int pp = 0; pp < 2; ++pp)
#pragma unroll
    for (int dt = 0; dt < 4; ++dt) acc[pp][dt] = (f32x4){0.f, 0.f, 0.f, 0.f};
  const size_t kbase = (size_t)bh * 65536;

  for (int n0 = 0; n0 < 1024; n0 += 64) {
    __syncthreads();
    for (int L = t; L < 512; L += 256) {
      const int r = L >> 3, c = (L & 7) << 3;
      *reinterpret_cast<short8*>(Ks + r * 72 + c) =
          *reinterpret_cast<const short8*>(kg + kbase + (size_t)(n0 + r) * 64 + c);
      *reinterpret_cast<short8*>(Vts + r * 72 + c) =
          *reinterpret_cast<const short8*>(vtg + kbase + (size_t)r * 1024 + n0 + c);
    }
    __syncthreads();
    short8 kf[4][2];
#pragma unroll
    for (int tile = 0; tile < 4; ++tile)
#pragma unroll
      for (int h = 0; h < 2; ++h)
        kf[tile][h] = *reinterpret_cast<const short8*>(Ks + (tile * 16 + l) * 72 + h * 32 + g * 8);
    bf16x4 pf[2][4];
#pragma unroll
    for (int pp = 0; pp < 2; ++pp) {
      f32x4 s[4];
#pragma unroll
      for (int tile = 0; tile < 4; ++tile) {
        s[tile] = (f32x4){0.f, 0.f, 0.f, 0.f};
#pragma unroll
        for (int h = 0; h < 2; ++h)
          s[tile] = __builtin_amdgcn_mfma_f32_16x16x32_bf16(kf[tile][h], tf[pp][h], s[tile], 0, 0, 0);
      }
      float p[4][4];
      float tmax = -1e30f;
#pragma unroll
      for (int tile = 0; tile < 4; ++tile)
#pragma unroll
        for (int r = 0; r < 4; ++r) {
          const float v = s[tile][r] * 0.125f;
          p[tile][r] = v;
          tmax = fmaxf(tmax, v);
        }
      tmax = fmaxf(tmax, __shfl_xor(tmax, 16));
      tmax = fmaxf(tmax, __shfl_xor(tmax, 32));
      const float nm = fmaxf(Mo[pp], tmax);
      const float al = __expf(Mo[pp] - nm);
      Mo[pp] = nm;
      float ps = 0.f;
#pragma unroll
      for (int tile = 0; tile < 4; ++tile)
#pragma unroll
        for (int r = 0; r < 4; ++r) {
          const float e = __expf(p[tile][r] - nm);
          p[tile][r] = e;
          ps += e;
        }
      ps += __shfl_xor(ps, 16);
      ps += __shfl_xor(ps, 32);
      Lo[pp] = Lo[pp] * al + ps;
#pragma unroll
      for (int tile = 0; tile < 4; ++tile) {
        bf16x4 pk;
        pk[0] = (short)f2bf(p[tile][0]); pk[1] = (short)f2bf(p[tile][1]);
        pk[2] = (short)f2bf(p[tile][2]); pk[3] = (short)f2bf(p[tile][3]);
        pf[pp][tile] = pk;
      }
      float ar[4];
#pragma unroll
      for (int r = 0; r < 4; ++r) ar[r] = __shfl(al, 4 * g + r);
#pragma unroll
      for (int dt = 0; dt < 4; ++dt)
#pragma unroll
        for (int r = 0; r < 4; ++r) acc[pp][dt][r] *= ar[r];
    }
#pragma unroll
    for (int tile = 0; tile < 4; ++tile)
#pragma unroll
      for (int dt = 0; dt < 4; ++dt) {
        const bf16x4 vf = *reinterpret_cast<const bf16x4*>(Vts + (dt * 16 + l) * 72 + tile * 16 + g * 4);
        acc[0][dt] = __builtin_amdgcn_mfma_f32_16x16x16bf16_1k(pf[0][tile], vf, acc[0][dt], 0, 0, 0);
        acc[1][dt] = __builtin_amdgcn_mfma_f32_16x16x16bf16_1k(pf[1][tile], vf, acc[1][dt], 0, 0, 0);
      }
  }
  const float inv0 = 1.f / Lo[0], inv1 = 1.f / Lo[1];
  float i1r[4], i2r[4];
#pragma unroll
  for (int r = 0; r < 4; ++r) {
    i1r[r] = __shfl(inv0, 4 * g + r);
    i2r[r] = __shfl(inv1, 4 * g + r);
  }
  const float lam1 = lam1p[0];
  float od[4][4], ss[4] = {0.f, 0.f, 0.f, 0.f};
#pragma unroll
  for (int dt = 0; dt < 4; ++dt)
#pragma unroll
    for (int r = 0; r < 4; ++r) {
      const float v = acc[0][dt][r] * i1r[r] - lam1 * (acc[1][dt][r] * i2r[r]);
      od[dt][r] = v;
      ss[r] += v * v;
    }
#pragma unroll
  for (int r = 0; r < 4; ++r) {
    ss[r] += __shfl_xor(ss[r], 1);
    ss[r] += __shfl_xor(ss[r], 2);
    ss[r] += __shfl_xor(ss[r], 4);
    ss[r] += __shfl_xor(ss[r], 8);
  }
  float sc[4];
#pragma unroll
  for (int r = 0; r < 4; ++r) sc[r] = 0.5f / (sqrtf(ss[r]) * 0.125f + 1e-6f);
  const int mb = w * 16 + 4 * g;
#pragma unroll
  for (int dt = 0; dt < 4; ++dt) {
    const int dd = dt * 16 + l;
    const float nw = norm1_w[dd];
#pragma unroll
    for (int r = 0; r < 4; ++r)
      vct[(size_t)bh * 4096 + dd * 64 + mb + r] = od[dt][r] * sc[r] * nw;
  }
}

// ---- K4: stage-2 MFMA attention + rmsnorm -> out_patch bf16 ---------------
__global__ __launch_bounds__(256) void stage2_kernel(const unsigned short* __restrict__ qg,
    const unsigned short* __restrict__ tpb, const unsigned short* __restrict__ tnb,
    const float* __restrict__ vct, const float* __restrict__ lam2p,
    const float* __restrict__ norm2_w, unsigned short* __restrict__ opb) {
  const int bh = blockIdx.x;
  const int q0 = blockIdx.y * 64;
  __shared__ unsigned short tp[64 * 72], tn[64 * 72], Qs[64 * 72], Vc[64 * 72];
  const int t = threadIdx.x;
  const int lane = t & 63;
  const int w = t >> 6;
  const int l = lane & 15, g = lane >> 4;
  for (int L = t; L < 512; L += 256) {
    const int r = L >> 3, c = (L & 7) << 3;
    *reinterpret_cast<short8*>(tp + r * 72 + c) =
        *reinterpret_cast<const short8*>(tpb + (size_t)bh * 4096 + r * 64 + c);
    *reinterpret_cast<short8*>(tn + r * 72 + c) =
        *reinterpret_cast<const short8*>(tnb + (size_t)bh * 4096 + r * 64 + c);
    *reinterpret_cast<short8*>(Qs + r * 72 + c) =
        *reinterpret_cast<const short8*>(qg + (size_t)bh * 65536 + (size_t)(q0 + r) * 64 + c);
  }
  for (int L = t; L < 4096; L += 256) {
    const int dd = L >> 6, m = L & 63;
    Vc[dd * 72 + m] = f2bf(vct[(size_t)bh * 4096 + L]);
  }
  __syncthreads();
  short8 qf[2];
#pragma unroll
  for (int h = 0; h < 2; ++h)
    qf[h] = *reinterpret_cast<const short8*>(Qs + (w * 16 + l) * 72 + h * 32 + g * 8);
  bf16x4 vcf[4][4];
#pragma unroll
  for (int tile = 0; tile < 4; ++tile)
#pragma unroll
    for (int dt = 0; dt < 4; ++dt)
      vcf[tile][dt] = *reinterpret_cast<const bf16x4*>(Vc + (dt * 16 + l) * 72 + tile * 16 + g * 4);
  bf16x4 pf[2][4];
#pragma unroll
  for (int pp = 0; pp < 2; ++pp) {
    const unsigned short* tm = pp ? tn : tp;
    f32x4 s[4];
#pragma unroll
    for (int tile = 0; tile < 4; ++tile) {
      s[tile] = (f32x4){0.f, 0.f, 0.f, 0.f};
#pragma unroll
      for (int h = 0; h < 2; ++h) {
        const short8 tfb = *reinterpret_cast<const short8*>(tm + (tile * 16 + l) * 72 + h * 32 + g * 8);
        s[tile] = __builtin_amdgcn_mfma_f32_16x16x32_bf16(tfb, qf[h], s[tile], 0, 0, 0);
      }
    }
    float p[4][4];
    float lmax = -1e30f;
#pragma unroll
    for (int tile = 0; tile < 4; ++tile)
#pragma unroll
      for (int r = 0; r < 4; ++r) {
        const float v = s[tile][r] * 0.125f;
        p[tile][r] = v;
        lmax = fmaxf(lmax, v);
      }
    lmax = fmaxf(lmax, __shfl_xor(lmax, 16));
    lmax = fmaxf(lmax, __shfl_xor(lmax, 32));
    float ps = 0.f;
#pragma unroll
    for (int tile = 0; tile < 4; ++tile)
#pragma unroll
      for (int r = 0; r < 4; ++r) {
        const float e = __expf(p[tile][r] - lmax);
        p[tile][r] = e;
        ps += e;
      }
    ps += __shfl_xor(ps, 16);
    ps += __shfl_xor(ps, 32);
    const float inv = 1.f / ps;
#pragma unroll
    for (int tile = 0; tile < 4; ++tile) {
      bf16x4 pk;
      pk[0] = (short)f2bf(p[tile][0] * inv); pk[1] = (short)f2bf(p[tile][1] * inv);
      pk[2] = (short)f2bf(p[tile][2] * inv); pk[3] = (short)f2bf(p[tile][3] * inv);
      pf[pp][tile] = pk;
    }
  }
  f32x4 a1[4], a2[4];
#pragma unroll
  for (int dt = 0; dt < 4; ++dt) {
    a1[dt] = (f32x4){0.f, 0.f, 0.f, 0.f};
    a2[dt] = (f32x4){0.f, 0.f, 0.f, 0.f};
  }
#pragma unroll
  for (int tile = 0; tile < 4; ++tile)
#pragma unroll
    for (int dt = 0; dt < 4; ++dt) {
      a1[dt] = __builtin_amdgcn_mfma_f32_16x16x16bf16_1k(pf[0][tile], vcf[tile][dt], a1[dt], 0, 0, 0);
      a2[dt] = __builtin_amdgcn_mfma_f32_16x16x16bf16_1k(pf[1][tile], vcf[tile][dt], a2[dt], 0, 0, 0);
    }
  const float lam2 = lam2p[0];
  float od[4][4], ss[4] = {0.f, 0.f, 0.f, 0.f};
#pragma unroll
  for (int dt = 0; dt < 4; ++dt)
#pragma unroll
    for (int r = 0; r < 4; ++r) {
      const float v = a1[dt][r] - lam2 * a2[dt][r];
      od[dt][r] = v;
      ss[r] += v * v;
    }
#pragma unroll
  for (int r = 0; r < 4; ++r) {
    ss[r] += __shfl_xor(ss[r], 1);
    ss[r] += __shfl_xor(ss[r], 2);
    ss[r] += __shfl_xor(ss[r], 4);
    ss[r] += __shfl_xor(ss[r], 8);
  }
  float sc[4];
#pragma unroll
  for (int r = 0; r < 4; ++r) sc[r] = 0.5f / (sqrtf(ss[r]) * 0.125f + 1e-6f);
  const int b = bh / 12, head = bh % 12;
  const size_t ob = ((size_t)b * 1024 + q0 + w * 16 + 4 * g) * 768 + head * 64;
#pragma unroll
  for (int dt = 0; dt < 4; ++dt) {
    const float nw = norm2_w[dt * 16 + l];
#pragma unroll
    for (int r = 0; r < 4; ++r)
      opb[ob + (size_t)r * 768 + dt * 16 + l] = f2bf(od[dt][r] * sc[r] * nw);
  }
}

// ---- K5: projection GEMM (128^2 2-phase dbuf), +bias, f32 out -------------
DEV void stage_tile(const unsigned short* __restrict__ A,
                    const unsigned short* __restrict__ Bm,
                    unsigned short* As, unsigned short* Bs,
                    int row0, int col0, int k0, int w, int srow, int scol) {
#pragma unroll
  for (int kc = 0; kc < 2; ++kc)
#pragma unroll
    for (int j = 0; j < 2; ++j) {
      const int qs = w * 2 + j;
      const int r = qs * 16 + srow;
      const int cg = k0 + kc * 32 + scol;
      gload16(A + (size_t)(row0 + r) * 768 + cg, As + kc * 4096 + qs * 512);
      gload16(Bm + (size_t)(col0 + r) * 768 + cg, Bs + kc * 4096 + qs * 512);
    }
}

__global__ __launch_bounds__(256) void gemm_proj_kernel(const unsigned short* __restrict__ A,
    const unsigned short* __restrict__ Bm, const float* __restrict__ bias,
    float* __restrict__ out) {
  __shared__ unsigned short As[2][8192];
  __shared__ unsigned short Bs[2][8192];
  const int t = threadIdx.x;
  const int lane = t & 63;
  const int w = t >> 6;
  const int wm = w >> 1, wn = w & 1;
  const int id = blockIdx.x;
  const int swz = (id & 7) * 192 + (id >> 3);
  const int row0 = (swz / 6) * 128;
  const int col0 = (swz % 6) * 128;
  f32x4 acc[4][4];
#pragma unroll
  for (int i = 0; i < 4; ++i)
#pragma unroll
    for (int j = 0; j < 4; ++j) acc[i][j] = (f32x4){0.f, 0.f, 0.f, 0.f};
  const int l = lane & 15, g = lane >> 4;
  const int srow = lane >> 2, scol = (lane & 3) << 3;

  stage_tile(A, Bm, As[0], Bs[0], row0, col0, 0, w, srow, scol);
  __syncthreads();
  for (int kt = 0; kt < 12; ++kt) {
    const int cur = kt & 1;
    if (kt < 11)
      stage_tile(A, Bm, As[cur ^ 1], Bs[cur ^ 1], row0, col0, (kt + 1) * 64, w, srow, scol);
#pragma unroll
    for (int kc = 0; kc < 2; ++kc) {
      short8 af[4], bfv[4];
#pragma unroll
      for (int mt = 0; mt < 4; ++mt)
        af[mt] = *reinterpret_cast<const short8*>(As[cur] + kc * 4096 + (wm * 64 + mt * 16 + l) * 32 + g * 8);
#pragma unroll
      for (int nt = 0; nt < 4; ++nt)
        bfv[nt] = *reinterpret_cast<const short8*>(Bs[cur] + kc * 4096 + (wn * 64 + nt * 16 + l) * 32 + g * 8);
#pragma unroll
      for (int mt = 0; mt < 4; ++mt)
#pragma unroll
        for (int nt = 0; nt < 4; ++nt)
          acc[mt][nt] = __builtin_amdgcn_mfma_f32_16x16x32_bf16(af[mt], bfv[nt], acc[mt][nt], 0, 0, 0);
    }
    __syncthreads();
  }
#pragma unroll
  for (int nt = 0; nt < 4; ++nt) {
    const int col = col0 + wn * 64 + nt * 16 + l;
    const float bv = bias[col];
#pragma unroll
    for (int mt = 0; mt < 4; ++mt)
#pragma unroll
      for (int r = 0; r < 4; ++r) {
        const int row = row0 + wm * 64 + mt * 16 + (g << 2) + r;
        out[(size_t)row * 768 + col] = acc[mt][nt][r] + bv;
      }
  }
}

// ---------------------------------------------------------------------------
extern "C" void kernel_launch(void* const* d_in, const int* in_sizes, int n_in,
                              void* d_out, int out_size, void* d_ws, size_t ws_size,
                              hipStream_t stream) {
  (void)in_sizes; (void)n_in; (void)out_size; (void)ws_size;
  const float* x       = (const float*)d_in[0];
  const float* Wqkv    = (const float*)d_in[1];
  const float* Wproj   = (const float*)d_in[2];
  const float* bproj   = (const float*)d_in[3];
  const float* Wpos    = (const float*)d_in[4];
  const float* Wneg    = (const float*)d_in[5];
  const float* conv_w  = (const float*)d_in[6];
  const float* lam1    = (const float*)d_in[7];
  const float* lam2    = (const float*)d_in[8];
  const float* norm1_w = (const float*)d_in[9];
  const float* norm2_w = (const float*)d_in[10];
  float* out = (float*)d_out;
  char* ws = (char*)d_ws;
  unsigned short* qb   = (unsigned short*)(ws + OFF_Q);
  unsigned short* kb   = (unsigned short*)(ws + OFF_K);
  unsigned short* vtb  = (unsigned short*)(ws + OFF_VT);
  unsigned short* tpbb = (unsigned short*)(ws + OFF_TPB);
  unsigned short* tnbb = (unsigned short*)(ws + OFF_TNB);
  float* vctb          = (float*)(ws + OFF_VCT);
  unsigned short* opb  = (unsigned short*)(ws + OFF_OP);
  unsigned short* xb   = (unsigned short*)(ws + OFF_XB);
  unsigned short* wqb  = (unsigned short*)(ws + OFF_WQ);
  unsigned short* wpb  = (unsigned short*)(ws + OFF_WP);
  float* epb           = (float*)(ws + OFF_EP);
  float* enb           = (float*)(ws + OFF_EN);

  cast_kernel<<<dim3(6291456 / 256), dim3(256), 0, stream>>>(x, xb, 6291456);
  cast_kernel<<<dim3(442368 / 256), dim3(256), 0, stream>>>(Wqkv, wqb, 442368);
  cast_kernel<<<dim3(147456 / 256), dim3(256), 0, stream>>>(Wproj, wpb, 147456);
  gemm_qkv_kernel<<<dim3(1152), dim3(512), 0, stream>>>(xb, wqb, qb, kb, vtb);
  gq_embed_kernel<<<dim3(384), dim3(256), 0, stream>>>(qb, Wpos, Wneg, epb, enb);
  conv_pool_kernel<<<dim3(384, 4), dim3(256), 0, stream>>>(qb, conv_w, epb, enb, tpbb, tnbb);
  stage1_kernel<<<dim3(384), dim3(256), 0, stream>>>(kb, vtb, tpbb, tnbb, lam1, norm1_w, vctb);
  stage2_kernel<<<dim3(384, 16), dim3(256), 0, stream>>>(qb, tpbb, tnbb, vctb, lam2, norm2_w, opb);
  gemm_proj_kernel<<<dim3(1536), dim3(256), 0, stream>>>(opb, wpb, bproj, out);
}

// Round 7
// 389.389 us; speedup vs baseline: 1.2195x; 1.1175x over previous
//
#include <hip/hip_runtime.h>
#include <hip/hip_bf16.h>

// ---------------------------------------------------------------------------
// VisualContrastAttention on MI355X (gfx950)
// B=32, N=1024 (32x32), C=768, heads=12, hd=64, pool 8x8=64 tokens
// Pipeline:
//   K0  cast x/Wqkv/Wproj f32->bf16
//   K1  qkv GEMM: 256x256, 8-wave, 8-phase counted-vmcnt (T1+T2+T3/T4+T5)
//   K2a gq reduction + Wpos/Wneg embeddings -> ep/en
//   K2b depthwise conv3x3+GELU+avgpool -> t_pos/t_neg (bf16)
//   K3  stage-1 flash attn: gload_lds double-buffered KV staging (XOR swizzle),
//       one barrier per tile; writes v_contrast bf16 vct[bh][d][m]
//   K4  stage-2 MFMA attention + rmsnorm -> out_patch bf16
//   K5  proj GEMM: 128x256, 8-wave, 2-phase counted-vmcnt + bias -> f32
// ---------------------------------------------------------------------------

typedef __attribute__((ext_vector_type(8))) short short8;
typedef __attribute__((ext_vector_type(4))) short bf16x4;
typedef __attribute__((ext_vector_type(4))) float f32x4;

#define DEV static __device__ __forceinline__

DEV unsigned short f2bf(float f) {
  unsigned int b; __builtin_memcpy(&b, &f, 4);
  unsigned int r = (b + 0x7FFFu + ((b >> 16) & 1u)) >> 16;
  return (unsigned short)r;
}
DEV float bf2f(unsigned short u) {
  unsigned int b = ((unsigned int)u) << 16;
  float f; __builtin_memcpy(&f, &b, 4);
  return f;
}

DEV void gload16(const unsigned short* g, unsigned short* l) {
  __builtin_amdgcn_global_load_lds(
      (const __attribute__((address_space(1))) unsigned int*)g,
      (__attribute__((address_space(3))) unsigned int*)l, 16, 0, 0);
}

DEV void bar() {
  asm volatile("" ::: "memory");
  __builtin_amdgcn_s_barrier();
  asm volatile("" ::: "memory");
}
DEV void wait_vm4() { asm volatile("s_waitcnt vmcnt(4)" ::: "memory"); __builtin_amdgcn_sched_barrier(0); }
DEV void wait_vm0() { asm volatile("s_waitcnt vmcnt(0)" ::: "memory"); __builtin_amdgcn_sched_barrier(0); }
DEV void wait_lgkm0() { asm volatile("s_waitcnt lgkmcnt(0)" ::: "memory"); __builtin_amdgcn_sched_barrier(0); }

// ---- workspace layout (bytes) ---------------------------------------------
constexpr size_t SZ_QKV = (size_t)32 * 12 * 1024 * 64 * 2;   // 50331648 bf16
constexpr size_t OFF_Q   = 0;
constexpr size_t OFF_K   = OFF_Q + SZ_QKV;
constexpr size_t OFF_VT  = OFF_K + SZ_QKV;                    // vt[bh][d][n] bf16
constexpr size_t OFF_TPB = OFF_VT + SZ_QKV;                   // bf16 384*64*64
constexpr size_t OFF_TNB = OFF_TPB + 3145728;
constexpr size_t OFF_VCT = OFF_TNB + 3145728;                 // bf16 vct[bh][d][m]
constexpr size_t OFF_OP  = OFF_VCT + 6291456;                 // bf16 32768*768
constexpr size_t OFF_XB  = OFF_OP + SZ_QKV;
constexpr size_t OFF_WQ  = OFF_XB + SZ_QKV;
constexpr size_t OFF_WP  = OFF_WQ + 3538944;
constexpr size_t OFF_EP  = OFF_WP + 1179648;                  // f32 384*64
constexpr size_t OFF_EN  = OFF_EP + 98304;

// ---- K0: f32 -> bf16 cast --------------------------------------------------
__global__ __launch_bounds__(256) void cast_kernel(const float* __restrict__ src,
                                                   unsigned short* __restrict__ dst, int n4) {
  int i = blockIdx.x * 256 + threadIdx.x;
  if (i >= n4) return;
  float4 v = reinterpret_cast<const float4*>(src)[i];
  ushort4 o;
  o.x = f2bf(v.x); o.y = f2bf(v.y); o.z = f2bf(v.z); o.w = f2bf(v.w);
  reinterpret_cast<ushort4*>(dst)[i] = o;
}

// stage 128 rows x 64 cols (stride-768 source) with XOR-swizzled source chunks
DEV void stage_ht(const unsigned short* __restrict__ G, unsigned short* shbase,
                  int grow0, int k0, int htrow0, int w, int lane) {
  const int rl = lane >> 3;
  const int ck = (lane & 7) ^ rl;
  const unsigned short* s0 = G + (size_t)(grow0 + htrow0 + w * 16 + rl) * 768 + k0 + ck * 8;
  gload16(s0, shbase + (htrow0 + w * 16) * 64);
  gload16(s0 + (size_t)8 * 768, shbase + (htrow0 + w * 16 + 8) * 64);
}

// ---- K1: qkv GEMM, 256^2 8-phase (unchanged from round 6, verified) -------
__global__ __launch_bounds__(512, 2) void gemm_qkv_kernel(const unsigned short* __restrict__ A,
    const unsigned short* __restrict__ Bm, unsigned short* __restrict__ q,
    unsigned short* __restrict__ k, unsigned short* __restrict__ vt) {
  __shared__ __align__(16) unsigned short sh[65536];   // 128 KiB
  const int t = threadIdx.x;
  const int lane = t & 63;
  const int w = t >> 6;
  const int wm = w >> 2, wn = w & 3;
  const int l = lane & 15, g = lane >> 4;
  const int id = blockIdx.x;
  const int swz = (id & 7) * 144 + (id >> 3);
  const int rt = swz / 9, ct = swz % 9;
  const int row0 = rt * 256, col0 = ct * 256;

  f32x4 acc[8][4];
#pragma unroll
  for (int i = 0; i < 8; ++i)
#pragma unroll
    for (int j = 0; j < 4; ++j) acc[i][j] = (f32x4){0.f, 0.f, 0.f, 0.f};

  stage_ht(A, sh, row0, 0, 0, w, lane);
  stage_ht(A, sh, row0, 0, 128, w, lane);
  stage_ht(Bm, sh + 32768, col0, 0, 0, w, lane);
  stage_ht(Bm, sh + 32768, col0, 0, 128, w, lane);
  stage_ht(Bm, sh + 32768 + 16384, col0, 64, 0, w, lane);
  stage_ht(Bm, sh + 32768 + 16384, col0, 64, 128, w, lane);
  wait_vm4();
  bar();

  for (int m = 0; m < 12; ++m) {
    const int d = m & 1;
    const unsigned short* Ab = sh + d * 16384;
    const unsigned short* Bb = sh + 32768 + d * 16384;
    short8 af[4][2], bf0[2][2], bf1[2][2];
    // p1
#pragma unroll
    for (int mt = 0; mt < 4; ++mt)
#pragma unroll
      for (int kc = 0; kc < 2; ++kc) {
        const int r = wm * 128 + mt * 16 + l;
        af[mt][kc] = *reinterpret_cast<const short8*>(Ab + r * 64 + (((kc << 2) | g) ^ (r & 7)) * 8);
      }
#pragma unroll
    for (int nt = 0; nt < 2; ++nt)
#pragma unroll
      for (int kc = 0; kc < 2; ++kc) {
        const int r = wn * 64 + nt * 16 + l;
        bf0[nt][kc] = *reinterpret_cast<const short8*>(Bb + r * 64 + (((kc << 2) | g) ^ (r & 7)) * 8);
      }
    if (m + 1 < 12) stage_ht(A, sh + (d ^ 1) * 16384, row0, (m + 1) * 64, 0, w, lane);
    bar();
    __builtin_amdgcn_s_setprio(1);
#pragma unroll
    for (int kc = 0; kc < 2; ++kc)
#pragma unroll
      for (int mt = 0; mt < 4; ++mt)
#pragma unroll
        for (int nt = 0; nt < 2; ++nt)
          acc[mt][nt] = __builtin_amdgcn_mfma_f32_16x16x32_bf16(af[mt][kc], bf0[nt][kc], acc[mt][nt], 0, 0, 0);
    __builtin_amdgcn_s_setprio(0);
    bar();
    // p2
#pragma unroll
    for (int nt = 0; nt < 2; ++nt)
#pragma unroll
      for (int kc = 0; kc < 2; ++kc) {
        const int r = wn * 64 + 32 + nt * 16 + l;
        bf1[nt][kc] = *reinterpret_cast<const short8*>(Bb + r * 64 + (((kc << 2) | g) ^ (r & 7)) * 8);
      }
    if (m + 1 < 12) stage_ht(A, sh + (d ^ 1) * 16384, row0, (m + 1) * 64, 128, w, lane);
    bar();
    __builtin_amdgcn_s_setprio(1);
#pragma unroll
    for (int kc = 0; kc < 2; ++kc)
#pragma unroll
      for (int mt = 0; mt < 4; ++mt)
#pragma unroll
        for (int nt = 0; nt < 2; ++nt)
          acc[mt][2 + nt] = __builtin_amdgcn_mfma_f32_16x16x32_bf16(af[mt][kc], bf1[nt][kc], acc[mt][2 + nt], 0, 0, 0);
    __builtin_amdgcn_s_setprio(0);
    bar();
    // p3
#pragma unroll
    for (int mt = 0; mt < 4; ++mt)
#pragma unroll
      for (int kc = 0; kc < 2; ++kc) {
        const int r = wm * 128 + 64 + mt * 16 + l;
        af[mt][kc] = *reinterpret_cast<const short8*>(Ab + r * 64 + (((kc << 2) | g) ^ (r & 7)) * 8);
      }
    if (m + 2 < 12) stage_ht(Bm, sh + 32768 + d * 16384, col0, (m + 2) * 64, 0, w, lane);
    bar();
    __builtin_amdgcn_s_setprio(1);
#pragma unroll
    for (int kc = 0; kc < 2; ++kc)
#pragma unroll
      for (int mt = 0; mt < 4; ++mt)
#pragma unroll
        for (int nt = 0; nt < 2; ++nt)
          acc[4 + mt][2 + nt] = __builtin_amdgcn_mfma_f32_16x16x32_bf16(af[mt][kc], bf1[nt][kc], acc[4 + mt][2 + nt], 0, 0, 0);
    __builtin_amdgcn_s_setprio(0);
    bar();
    // p4
    if (m + 2 < 12) stage_ht(Bm, sh + 32768 + d * 16384, col0, (m + 2) * 64, 128, w, lane);
    bar();
    __builtin_amdgcn_s_setprio(1);
#pragma unroll
    for (int kc = 0; kc < 2; ++kc)
#pragma unroll
      for (int mt = 0; mt < 4; ++mt)
#pragma unroll
        for (int nt = 0; nt < 2; ++nt)
          acc[4 + mt][nt] = __builtin_amdgcn_mfma_f32_16x16x32_bf16(af[mt][kc], bf0[nt][kc], acc[4 + mt][nt], 0, 0, 0);
    __builtin_amdgcn_s_setprio(0);
    if (m < 11) {
      if (m == 10) wait_vm0(); else wait_vm4();
    }
    bar();
  }

  const int s_ = ct / 3;
  if (s_ == 2) {
#pragma unroll
    for (int ni = 0; ni < 4; ++ni) {
      const int colg = (ct % 3) * 256 + wn * 64 + ni * 16 + l;
      const int head = colg >> 6, dd = colg & 63;
#pragma unroll
      for (int mi = 0; mi < 8; ++mi) {
        const int row = row0 + wm * 128 + mi * 16 + (g << 2);
        const int b = row >> 10, n = row & 1023;
        ushort4 pk;
        pk.x = f2bf(acc[mi][ni][0]); pk.y = f2bf(acc[mi][ni][1]);
        pk.z = f2bf(acc[mi][ni][2]); pk.w = f2bf(acc[mi][ni][3]);
        *reinterpret_cast<ushort4*>(vt + ((((size_t)b * 12 + head) * 64 + dd) << 10) + n) = pk;
      }
    }
  } else {
    unsigned short* dst = (s_ == 0) ? q : k;
#pragma unroll
    for (int ni = 0; ni < 4; ++ni) {
      const int colg = (ct % 3) * 256 + wn * 64 + ni * 16 + l;
      const int head = colg >> 6, dd = colg & 63;
#pragma unroll
      for (int mi = 0; mi < 8; ++mi) {
#pragma unroll
        for (int r = 0; r < 4; ++r) {
          const int row = row0 + wm * 128 + mi * 16 + (g << 2) + r;
          const int b = row >> 10, n = row & 1023;
          dst[(((size_t)b * 12 + head) * 1024 + n) * 64 + dd] = f2bf(acc[mi][ni][r]);
        }
      }
    }
  }
}

// ---- K2a: gq reduction + e+/e- embeddings ---------------------------------
__global__ __launch_bounds__(256) void gq_embed_kernel(const unsigned short* __restrict__ qg,
    const float* __restrict__ Wpos, const float* __restrict__ Wneg,
    float* __restrict__ ep, float* __restrict__ en) {
  const int bh = blockIdx.x;
  const unsigned short* qp = qg + (size_t)bh * 65536;
  __shared__ float red2[32][64];
  __shared__ float gq_s[64];
  const int t = threadIdx.x;
  const int c8 = (t & 7) << 3;
  const int part = t >> 3;
  float s[8] = {0.f, 0.f, 0.f, 0.f, 0.f, 0.f, 0.f, 0.f};
  for (int i = 0; i < 32; ++i) {
    const short8 v = *reinterpret_cast<const short8*>(qp + (size_t)(part * 32 + i) * 64 + c8);
#pragma unroll
    for (int j = 0; j < 8; ++j) s[j] += bf2f((unsigned short)v[j]);
  }
#pragma unroll
  for (int j = 0; j < 8; ++j) red2[part][c8 + j] = s[j];
  __syncthreads();
  if (t < 64) {
    float s2 = 0.f;
    for (int p = 0; p < 32; ++p) s2 += red2[p][t];
    gq_s[t] = s2 * (1.0f / 1024.0f);
  }
  __syncthreads();
  if (t < 128) {
    const int d2 = t & 63;
    const float* Wm = (t < 64) ? Wpos : Wneg;
    float e = 0.f;
    for (int dd = 0; dd < 64; ++dd) e += gq_s[dd] * Wm[d2 * 64 + dd];
    (t < 64 ? ep : en)[bh * 64 + d2] = e;
  }
}

// ---- K2b: conv3x3 depthwise + GELU + 4x4 mean pool -> t_pos/t_neg ---------
__global__ __launch_bounds__(256) void conv_pool_kernel(const unsigned short* __restrict__ qg,
    const float* __restrict__ conv_w, const float* __restrict__ ep,
    const float* __restrict__ en, unsigned short* __restrict__ t_pos,
    unsigned short* __restrict__ t_neg) {
  const int bh = blockIdx.x;
  const int quad = blockIdx.y;
  const unsigned short* qp = qg + (size_t)bh * 65536;
  __shared__ float pool_s[16][64];
  const int t = threadIdx.x;
  const int dg = t & 7, sp = t >> 3;
  const int d0 = dg << 3;
  float cw[3][3][8];
#pragma unroll
  for (int ky = 0; ky < 3; ++ky)
#pragma unroll
    for (int kx = 0; kx < 3; ++kx)
#pragma unroll
      for (int j = 0; j < 8; ++j)
        cw[ky][kx][j] = conv_w[(d0 + j) * 9 + ky * 3 + kx];
#pragma unroll
  for (int pyl = 0; pyl < 2; ++pyl) {
    float win[8] = {0.f, 0.f, 0.f, 0.f, 0.f, 0.f, 0.f, 0.f};
#pragma unroll
    for (int iy = 0; iy < 4; ++iy) {
      const int y = quad * 8 + pyl * 4 + iy;
      float a[8] = {0.f, 0.f, 0.f, 0.f, 0.f, 0.f, 0.f, 0.f};
#pragma unroll
      for (int ky = 0; ky < 3; ++ky) {
        const int yy = y + ky - 1;
        if (yy < 0 || yy > 31) continue;
#pragma unroll
        for (int kx = 0; kx < 3; ++kx) {
          const int xx = sp + kx - 1;
          if (xx < 0 || xx > 31) continue;
          const short8 v = *reinterpret_cast<const short8*>(qp + (size_t)(yy * 32 + xx) * 64 + d0);
#pragma unroll
          for (int j = 0; j < 8; ++j) a[j] += bf2f((unsigned short)v[j]) * cw[ky][kx][j];
        }
      }
#pragma unroll
      for (int j = 0; j < 8; ++j)
        win[j] += 0.5f * a[j] * (1.0f + erff(a[j] * 0.70710678118654752440f));
    }
#pragma unroll
    for (int j = 0; j < 8; ++j) {
      win[j] += __shfl_xor(win[j], 8);
      win[j] += __shfl_xor(win[j], 16);
    }
    if ((sp & 3) == 0) {
      const int px = sp >> 2;
#pragma unroll
      for (int j = 0; j < 8; ++j) pool_s[pyl * 8 + px][d0 + j] = win[j];
    }
  }
  __syncthreads();
#pragma unroll
  for (int i = 0; i < 4; ++i) {
    const int idx = i * 256 + t;
    const int m = idx >> 6, dd = idx & 63;
    const int mg = quad * 16 + m;
    const float base = pool_s[m][dd] * (1.0f / 16.0f);
    t_pos[(size_t)bh * 4096 + mg * 64 + dd] = f2bf(base + ep[bh * 64 + dd]);
    t_neg[(size_t)bh * 4096 + mg * 64 + dd] = f2bf(base + en[bh * 64 + dd]);
  }
}

// ---- K3: stage-1 flash attn, gload_lds dbuf staging, vct bf16 out ---------
// 4 waves; wave w owns t-strip w*16..+15.  K/V tiles 64x64 bf16 in linear
// [64][64] LDS, XOR-swizzled (source chunk ^ row&7; read chunk ^ row&7).
__global__ __launch_bounds__(256) void stage1_kernel(const unsigned short* __restrict__ kg,
    const unsigned short* __restrict__ vtg, const unsigned short* __restrict__ tpb,
    const unsigned short* __restrict__ tnb, const float* __restrict__ lam1p,
    const float* __restrict__ norm1_w, unsigned short* __restrict__ vct) {
  const int bh = blockIdx.x;
  __shared__ unsigned short tp[64 * 72], tn[64 * 72];
  __shared__ __align__(16) unsigned short Ks[2][4096];
  __shared__ __align__(16) unsigned short Vts[2][4096];
  const int t = threadIdx.x;
  const int lane = t & 63;
  const int w = t >> 6;
  const int l = lane & 15, g = lane >> 4;
  const size_t kbase = (size_t)bh * 65536;
  const int rl = lane >> 3, ck = (lane & 7) ^ rl;

  for (int L = t; L < 512; L += 256) {
    const int r = L >> 3, c = (L & 7) << 3;
    *reinterpret_cast<short8*>(tp + r * 72 + c) =
        *reinterpret_cast<const short8*>(tpb + (size_t)bh * 4096 + r * 64 + c);
    *reinterpret_cast<short8*>(tn + r * 72 + c) =
        *reinterpret_cast<const short8*>(tnb + (size_t)bh * 4096 + r * 64 + c);
  }
  // K rows n (stride 64), V rows d (stride 1024); each wave stages 16 rows x2
  auto stageKV = [&](int buf, int n0) {
    const unsigned short* ksrc = kg + kbase + (size_t)(n0 + w * 16 + rl) * 64 + ck * 8;
    gload16(ksrc, &Ks[buf][(w * 16) * 64]);
    gload16(ksrc + (size_t)8 * 64, &Ks[buf][(w * 16 + 8) * 64]);
    const unsigned short* vsrc = vtg + kbase + (size_t)(w * 16 + rl) * 1024 + n0 + ck * 8;
    gload16(vsrc, &Vts[buf][(w * 16) * 64]);
    gload16(vsrc + (size_t)8 * 1024, &Vts[buf][(w * 16 + 8) * 64]);
  };
  stageKV(0, 0);
  __syncthreads();   // drains lgkm (tp/tn writes) + vmcnt (stage) for all waves

  short8 tf[2][2];
#pragma unroll
  for (int h = 0; h < 2; ++h) {
    tf[0][h] = *reinterpret_cast<const short8*>(tp + (w * 16 + l) * 72 + h * 32 + g * 8);
    tf[1][h] = *reinterpret_cast<const short8*>(tn + (w * 16 + l) * 72 + h * 32 + g * 8);
  }
  float Mo[2] = {-1e30f, -1e30f}, Lo[2] = {0.f, 0.f};
  f32x4 acc[2][4];
#pragma unroll
  for (int pp = 0; pp < 2; ++pp)
#pragma unroll
    for (int dt = 0; dt < 4; ++dt) acc[pp][dt] = (f32x4){0.f, 0.f, 0.f, 0.f};

  for (int it = 0; it < 16; ++it) {
    const int buf = it & 1;
    if (it < 15) stageKV(buf ^ 1, (it + 1) * 64);
    short8 kf[4][2];
#pragma unroll
    for (int tile = 0; tile < 4; ++tile)
#pragma unroll
      for (int h = 0; h < 2; ++h) {
        const int R = tile * 16 + l;
        kf[tile][h] = *reinterpret_cast<const short8*>(&Ks[buf][R * 64 + ((((h << 2) | g)) ^ (l & 7)) * 8]);
      }
    bf16x4 pf[2][4];
#pragma unroll
    for (int pp = 0; pp < 2; ++pp) {
      f32x4 s[4];
#pragma unroll
      for (int tile = 0; tile < 4; ++tile) {
        s[tile] = (f32x4){0.f, 0.f, 0.f, 0.f};
#pragma unroll
        for (int h = 0; h < 2; ++h)
          s[tile] = __builtin_amdgcn_mfma_f32_16x16x32_bf16(kf[tile][h], tf[pp][h], s[tile], 0, 0, 0);
      }
      float p[4][4];
      float tmax = -1e30f;
#pragma unroll
      for (int tile = 0; tile < 4; ++tile)
#pragma unroll
        for (int r = 0; r < 4; ++r) {
          const float v = s[tile][r] * 0.125f;
          p[tile][r] = v;
          tmax = fmaxf(tmax, v);
        }
      tmax = fmaxf(tmax, __shfl_xor(tmax, 16));
      tmax = fmaxf(tmax, __shfl_xor(tmax, 32));
      const float nm = fmaxf(Mo[pp], tmax);
      const float al = __expf(Mo[pp] - nm);
      Mo[pp] = nm;
      float ps = 0.f;
#pragma unroll
      for (int tile = 0; tile < 4; ++tile)
#pragma unroll
        for (int r = 0; r < 4; ++r) {
          const float e = __expf(p[tile][r] - nm);
          p[tile][r] = e;
          ps += e;
        }
      ps += __shfl_xor(ps, 16);
      ps += __shfl_xor(ps, 32);
      Lo[pp] = Lo[pp] * al + ps;
#pragma unroll
      for (int tile = 0; tile < 4; ++tile) {
        bf16x4 pk;
        pk[0] = (short)f2bf(p[tile][0]); pk[1] = (short)f2bf(p[tile][1]);
        pk[2] = (short)f2bf(p[tile][2]); pk[3] = (short)f2bf(p[tile][3]);
        pf[pp][tile] = pk;
      }
      float ar[4];
#pragma unroll
      for (int r = 0; r < 4; ++r) ar[r] = __shfl(al, 4 * g + r);
#pragma unroll
      for (int dt = 0; dt < 4; ++dt)
#pragma unroll
        for (int r = 0; r < 4; ++r) acc[pp][dt][r] *= ar[r];
    }
#pragma unroll
    for (int tile = 0; tile < 4; ++tile)
#pragma unroll
      for (int dt = 0; dt < 4; ++dt) {
        const int R = dt * 16 + l;
        const bf16x4 vf = *reinterpret_cast<const bf16x4*>(
            &Vts[buf][R * 64 + (((2 * tile + (g >> 1)) ^ (l & 7)) * 8) + (g & 1) * 4]);
        acc[0][dt] = __builtin_amdgcn_mfma_f32_16x16x16bf16_1k(pf[0][tile], vf, acc[0][dt], 0, 0, 0);
        acc[1][dt] = __builtin_amdgcn_mfma_f32_16x16x16bf16_1k(pf[1][tile], vf, acc[1][dt], 0, 0, 0);
      }
    __syncthreads();   // full drain: prefetch landed; buffers safe to swap
  }
  const float inv0 = 1.f / Lo[0], inv1 = 1.f / Lo[1];
  float i1r[4], i2r[4];
#pragma unroll
  for (int r = 0; r < 4; ++r) {
    i1r[r] = __shfl(inv0, 4 * g + r);
    i2r[r] = __shfl(inv1, 4 * g + r);
  }
  const float lam1 = lam1p[0];
  float od[4][4], ss[4] = {0.f, 0.f, 0.f, 0.f};
#pragma unroll
  for (int dt = 0; dt < 4; ++dt)
#pragma unroll
    for (int r = 0; r < 4; ++r) {
      const float v = acc[0][dt][r] * i1r[r] - lam1 * (acc[1][dt][r] * i2r[r]);
      od[dt][r] = v;
      ss[r] += v * v;
    }
#pragma unroll
  for (int r = 0; r < 4; ++r) {
    ss[r] += __shfl_xor(ss[r], 1);
    ss[r] += __shfl_xor(ss[r], 2);
    ss[r] += __shfl_xor(ss[r], 4);
    ss[r] += __shfl_xor(ss[r], 8);
  }
  float sc[4];
#pragma unroll
  for (int r = 0; r < 4; ++r) sc[r] = 0.5f / (sqrtf(ss[r]) * 0.125f + 1e-6f);
  const int mb = w * 16 + 4 * g;
#pragma unroll
  for (int dt = 0; dt < 4; ++dt) {
    const int dd = dt * 16 + l;
    const float nw = norm1_w[dd];
    ushort4 pk;
    pk.x = f2bf(od[dt][0] * sc[0] * nw);
    pk.y = f2bf(od[dt][1] * sc[1] * nw);
    pk.z = f2bf(od[dt][2] * sc[2] * nw);
    pk.w = f2bf(od[dt][3] * sc[3] * nw);
    *reinterpret_cast<ushort4*>(vct + (size_t)bh * 4096 + dd * 64 + mb) = pk;
  }
}

// ---- K4: stage-2 MFMA attention + rmsnorm -> out_patch bf16 ---------------
__global__ __launch_bounds__(256) void stage2_kernel(const unsigned short* __restrict__ qg,
    const unsigned short* __restrict__ tpb, const unsigned short* __restrict__ tnb,
    const unsigned short* __restrict__ vctg, const float* __restrict__ lam2p,
    const float* __restrict__ norm2_w, unsigned short* __restrict__ opb) {
  const int bh = blockIdx.x;
  const int q0 = blockIdx.y * 64;
  __shared__ unsigned short tp[64 * 72], tn[64 * 72], Qs[64 * 72], Vc[64 * 72];
  const int t = threadIdx.x;
  const int lane = t & 63;
  const int w = t >> 6;
  const int l = lane & 15, g = lane >> 4;
  for (int L = t; L < 512; L += 256) {
    const int r = L >> 3, c = (L & 7) << 3;
    *reinterpret_cast<short8*>(tp + r * 72 + c) =
        *reinterpret_cast<const short8*>(tpb + (size_t)bh * 4096 + r * 64 + c);
    *reinterpret_cast<short8*>(tn + r * 72 + c) =
        *reinterpret_cast<const short8*>(tnb + (size_t)bh * 4096 + r * 64 + c);
    *reinterpret_cast<short8*>(Qs + r * 72 + c) =
        *reinterpret_cast<const short8*>(qg + (size_t)bh * 65536 + (size_t)(q0 + r) * 64 + c);
    *reinterpret_cast<short8*>(Vc + r * 72 + c) =
        *reinterpret_cast<const short8*>(vctg + (size_t)bh * 4096 + r * 64 + c);
  }
  __syncthreads();
  short8 qf[2];
#pragma unroll
  for (int h = 0; h < 2; ++h)
    qf[h] = *reinterpret_cast<const short8*>(Qs + (w * 16 + l) * 72 + h * 32 + g * 8);
  bf16x4 vcf[4][4];
#pragma unroll
  for (int tile = 0; tile < 4; ++tile)
#pragma unroll
    for (int dt = 0; dt < 4; ++dt)
      vcf[tile][dt] = *reinterpret_cast<const bf16x4*>(Vc + (dt * 16 + l) * 72 + tile * 16 + g * 4);
  bf16x4 pf[2][4];
#pragma unroll
  for (int pp = 0; pp < 2; ++pp) {
    const unsigned short* tm = pp ? tn : tp;
    f32x4 s[4];
#pragma unroll
    for (int tile = 0; tile < 4; ++tile) {
      s[tile] = (f32x4){0.f, 0.f, 0.f, 0.f};
#pragma unroll
      for (int h = 0; h < 2; ++h) {
        const short8 tfb = *reinterpret_cast<const short8*>(tm + (tile * 16 + l) * 72 + h * 32 + g * 8);
        s[tile] = __builtin_amdgcn_mfma_f32_16x16x32_bf16(tfb, qf[h], s[tile], 0, 0, 0);
      }
    }
    float p[4][4];
    float lmax = -1e30f;
#pragma unroll
    for (int tile = 0; tile < 4; ++tile)
#pragma unroll
      for (int r = 0; r < 4; ++r) {
        const float v = s[tile][r] * 0.125f;
        p[tile][r] = v;
        lmax = fmaxf(lmax, v);
      }
    lmax = fmaxf(lmax, __shfl_xor(lmax, 16));
    lmax = fmaxf(lmax, __shfl_xor(lmax, 32));
    float ps = 0.f;
#pragma unroll
    for (int tile = 0; tile < 4; ++tile)
#pragma unroll
      for (int r = 0; r < 4; ++r) {
        const float e = __expf(p[tile][r] - lmax);
        p[tile][r] = e;
        ps += e;
      }
    ps += __shfl_xor(ps, 16);
    ps += __shfl_xor(ps, 32);
    const float inv = 1.f / ps;
#pragma unroll
    for (int tile = 0; tile < 4; ++tile) {
      bf16x4 pk;
      pk[0] = (short)f2bf(p[tile][0] * inv); pk[1] = (short)f2bf(p[tile][1] * inv);
      pk[2] = (short)f2bf(p[tile][2] * inv); pk[3] = (short)f2bf(p[tile][3] * inv);
      pf[pp][tile] = pk;
    }
  }
  f32x4 a1[4], a2[4];
#pragma unroll
  for (int dt = 0; dt < 4; ++dt) {
    a1[dt] = (f32x4){0.f, 0.f, 0.f, 0.f};
    a2[dt] = (f32x4){0.f, 0.f, 0.f, 0.f};
  }
#pragma unroll
  for (int tile = 0; tile < 4; ++tile)
#pragma unroll
    for (int dt = 0; dt < 4; ++dt) {
      a1[dt] = __builtin_amdgcn_mfma_f32_16x16x16bf16_1k(pf[0][tile], vcf[tile][dt], a1[dt], 0, 0, 0);
      a2[dt] = __builtin_amdgcn_mfma_f32_16x16x16bf16_1k(pf[1][tile], vcf[tile][dt], a2[dt], 0, 0, 0);
    }
  const float lam2 = lam2p[0];
  float od[4][4], ss[4] = {0.f, 0.f, 0.f, 0.f};
#pragma unroll
  for (int dt = 0; dt < 4; ++dt)
#pragma unroll
    for (int r = 0; r < 4; ++r) {
      const float v = a1[dt][r] - lam2 * a2[dt][r];
      od[dt][r] = v;
      ss[r] += v * v;
    }
#pragma unroll
  for (int r = 0; r < 4; ++r) {
    ss[r] += __shfl_xor(ss[r], 1);
    ss[r] += __shfl_xor(ss[r], 2);
    ss[r] += __shfl_xor(ss[r], 4);
    ss[r] += __shfl_xor(ss[r], 8);
  }
  float sc[4];
#pragma unroll
  for (int r = 0; r < 4; ++r) sc[r] = 0.5f / (sqrtf(ss[r]) * 0.125f + 1e-6f);
  const int b = bh / 12, head = bh % 12;
  const size_t ob = ((size_t)b * 1024 + q0 + w * 16 + 4 * g) * 768 + head * 64;
#pragma unroll
  for (int dt = 0; dt < 4; ++dt) {
    const float nw = norm2_w[dt * 16 + l];
#pragma unroll
    for (int r = 0; r < 4; ++r)
      opb[ob + (size_t)r * 768 + dt * 16 + l] = f2bf(od[dt][r] * sc[r] * nw);
  }
}

// ---- K5: proj GEMM, 128x256 tile, 2-phase counted-vmcnt, +bias, f32 out ---
// Grid 768 (256 rowtiles x 3 coltiles), 512 thr (wm=w>>2 rows64, wn=w&3 cols64).
// LDS 96KB: A[2][128][64] @0, B[2][256][64] @16384 (ushort units).
// Per iter: p1 {read af+bf01, stage A(m+1), bar, 16 MFMA, bar};
//           p2 {read bf23, lgkm0, bar, stage B(m+2), 16 MFMA, vmcnt(4), bar}.
__global__ __launch_bounds__(512, 2) void gemm_proj_kernel(const unsigned short* __restrict__ A,
    const unsigned short* __restrict__ Bm, const float* __restrict__ bias,
    float* __restrict__ out) {
  __shared__ __align__(16) unsigned short sh[49152];   // 96 KiB
  const int t = threadIdx.x;
  const int lane = t & 63;
  const int w = t >> 6;
  const int wm = w >> 2, wn = w & 3;
  const int l = lane & 15, g = lane >> 4;
  const int id = blockIdx.x;                 // nwg = 768 = 8*96
  const int swz = (id & 7) * 96 + (id >> 3);
  const int rt = swz / 3, ct = swz % 3;
  const int row0 = rt * 128, col0 = ct * 256;

  f32x4 acc[4][4];
#pragma unroll
  for (int i = 0; i < 4; ++i)
#pragma unroll
    for (int j = 0; j < 4; ++j) acc[i][j] = (f32x4){0.f, 0.f, 0.f, 0.f};

  // prologue: A(0), B(0), B(1)
  stage_ht(A, sh, row0, 0, 0, w, lane);                         // A0 (128 rows)
  stage_ht(Bm, sh + 16384, col0, 0, 0, w, lane);                // B0 top
  stage_ht(Bm, sh + 16384, col0, 0, 128, w, lane);              // B0 bot
  stage_ht(Bm, sh + 32768, col0, 64, 0, w, lane);               // B1 top
  stage_ht(Bm, sh + 32768, col0, 64, 128, w, lane);             // B1 bot
  wait_vm4();
  bar();

  for (int m = 0; m < 12; ++m) {
    const int d = m & 1;
    const unsigned short* Ab = sh + d * 8192;
    const unsigned short* Bb = sh + 16384 + d * 16384;
    short8 af[4][2], bfv[4][2];
    // ---- p1 ----
#pragma unroll
    for (int mt = 0; mt < 4; ++mt)
#pragma unroll
      for (int kc = 0; kc < 2; ++kc) {
        const int r = wm * 64 + mt * 16 + l;
        af[mt][kc] = *reinterpret_cast<const short8*>(Ab + r * 64 + (((kc << 2) | g) ^ (r & 7)) * 8);
      }
#pragma unroll
    for (int nt = 0; nt < 2; ++nt)
#pragma unroll
      for (int kc = 0; kc < 2; ++kc) {
        const int r = wn * 64 + nt * 16 + l;
        bfv[nt][kc] = *reinterpret_cast<const short8*>(Bb + r * 64 + (((kc << 2) | g) ^ (r & 7)) * 8);
      }
    if (m + 1 < 12) stage_ht(A, sh + (d ^ 1) * 8192, row0, (m + 1) * 64, 0, w, lane);
    bar();
    __builtin_amdgcn_s_setprio(1);
#pragma unroll
    for (int kc = 0; kc < 2; ++kc)
#pragma unroll
      for (int mt = 0; mt < 4; ++mt)
#pragma unroll
        for (int nt = 0; nt < 2; ++nt)
          acc[mt][nt] = __builtin_amdgcn_mfma_f32_16x16x32_bf16(af[mt][kc], bfv[nt][kc], acc[mt][nt], 0, 0, 0);
    __builtin_amdgcn_s_setprio(0);
    bar();
    // ---- p2 ----
#pragma unroll
    for (int nt = 2; nt < 4; ++nt)
#pragma unroll
      for (int kc = 0; kc < 2; ++kc) {
        const int r = wn * 64 + nt * 16 + l;
        bfv[nt][kc] = *reinterpret_cast<const short8*>(Bb + r * 64 + (((kc << 2) | g) ^ (r & 7)) * 8);
      }
    wait_lgkm0();   // all waves' B reads done before the post-bar stage overwrites Bb
    bar();
    if (m + 2 < 12) {
      stage_ht(Bm, sh + 16384 + d * 16384, col0, (m + 2) * 64, 0, w, lane);
      stage_ht(Bm, sh + 16384 + d * 16384, col0, (m + 2) * 64, 128, w, lane);
    }
    __builtin_amdgcn_s_setprio(1);
#pragma unroll
    for (int kc = 0; kc < 2; ++kc)
#pragma unroll
      for (int mt = 0; mt < 4; ++mt)
#pragma unroll
        for (int nt = 2; nt < 4; ++nt)
          acc[mt][nt] = __builtin_amdgcn_mfma_f32_16x16x32_bf16(af[mt][kc], bfv[nt][kc], acc[mt][nt], 0, 0, 0);
    __builtin_amdgcn_s_setprio(0);
    if (m < 11) {
      if (m == 10) wait_vm0(); else wait_vm4();
    }
    bar();
  }
#pragma unroll
  for (int ni = 0; ni < 4; ++ni) {
    const int colg = ct * 256 + wn * 64 + ni * 16 + l;
    const float bv = bias[colg];
#pragma unroll
    for (int mi = 0; mi < 4; ++mi)
#pragma unroll
      for (int r = 0; r < 4; ++r) {
        const int row = row0 + wm * 64 + mi * 16 + (g << 2) + r;
        out[(size_t)row * 768 + colg] = acc[mi][ni][r] + bv;
      }
  }
}

// ---------------------------------------------------------------------------
extern "C" void kernel_launch(void* const* d_in, const int* in_sizes, int n_in,
                              void* d_out, int out_size, void* d_ws, size_t ws_size,
                              hipStream_t stream) {
  (void)in_sizes; (void)n_in; (void)out_size; (void)ws_size;
  const float* x       = (const float*)d_in[0];
  const float* Wqkv    = (const float*)d_in[1];
  const float* Wproj   = (const float*)d_in[2];
  const float* bproj   = (const float*)d_in[3];
  const float* Wpos    = (const float*)d_in[4];
  const float* Wneg    = (const float*)d_in[5];
  const float* conv_w  = (const float*)d_in[6];
  const float* lam1    = (const float*)d_in[7];
  const float* lam2    = (const float*)d_in[8];
  const float* norm1_w = (const float*)d_in[9];
  const float* norm2_w = (const float*)d_in[10];
  float* out = (float*)d_out;
  char* ws = (char*)d_ws;
  unsigned short* qb   = (unsigned short*)(ws + OFF_Q);
  unsigned short* kb   = (unsigned short*)(ws + OFF_K);
  unsigned short* vtb  = (unsigned short*)(ws + OFF_VT);
  unsigned short* tpbb = (unsigned short*)(ws + OFF_TPB);
  unsigned short* tnbb = (unsigned short*)(ws + OFF_TNB);
  unsigned short* vctb = (unsigned short*)(ws + OFF_VCT);
  unsigned short* opb  = (unsigned short*)(ws + OFF_OP);
  unsigned short* xb   = (unsigned short*)(ws + OFF_XB);
  unsigned short* wqb  = (unsigned short*)(ws + OFF_WQ);
  unsigned short* wpb  = (unsigned short*)(ws + OFF_WP);
  float* epb           = (float*)(ws + OFF_EP);
  float* enb           = (float*)(ws + OFF_EN);

  cast_kernel<<<dim3(6291456 / 256), dim3(256), 0, stream>>>(x, xb, 6291456);
  cast_kernel<<<dim3(442368 / 256), dim3(256), 0, stream>>>(Wqkv, wqb, 442368);
  cast_kernel<<<dim3(147456 / 256), dim3(256), 0, stream>>>(Wproj, wpb, 147456);
  gemm_qkv_kernel<<<dim3(1152), dim3(512), 0, stream>>>(xb, wqb, qb, kb, vtb);
  gq_embed_kernel<<<dim3(384), dim3(256), 0, stream>>>(qb, Wpos, Wneg, epb, enb);
  conv_pool_kernel<<<dim3(384, 4), dim3(256), 0, stream>>>(qb, conv_w, epb, enb, tpbb, tnbb);
  stage1_kernel<<<dim3(384), dim3(256), 0, stream>>>(kb, vtb, tpbb, tnbb, lam1, norm1_w, vctb);
  stage2_kernel<<<dim3(384, 16), dim3(256), 0, stream>>>(qb, tpbb, tnbb, vctb, lam2, norm2_w, opb);
  gemm_proj_kernel<<<dim3(768), dim3(512), 0, stream>>>(opb, wpb, bproj, out);
}